// Round 1
// baseline (15661.034 us; speedup 1.0000x reference)
//
#include <hip/hip_runtime.h>

#define KVOL 8
#define NIN 40000
#define NOUT 150000
#define C 128
#define EPSV 1e-5f

#define ROWS_IT 16
#define ITERS2 32
#define ITERS_G 16

__device__ __forceinline__ void fma4(float4& a, float s, float4 w) {
    a.x = fmaf(s, w.x, a.x);
    a.y = fmaf(s, w.y, a.y);
    a.z = fmaf(s, w.z, a.z);
    a.w = fmaf(s, w.w, a.w);
}

// ---------------- scatter gather-GEMM: up_raw[pout[k][p]] += x[pin[k][p]] @ Wup[k] ----------------
__global__ __launch_bounds__(256) void k_scatter_gemm(
    const float* __restrict__ x, const int* __restrict__ pin, const int* __restrict__ pout,
    const float* __restrict__ Wup, float* __restrict__ out)
{
    __shared__ float Wl[C * C];
    __shared__ float4 xr4[ROWS_IT][C / 4];
    const int t = threadIdx.x;
    const int k = blockIdx.y;
    for (int i = t; i < C * C; i += 256) Wl[i] = Wup[k * C * C + i];
    const float4* Wl4 = (const float4*)Wl;
    const int l = t & 31;        // 4-channel lane: channels l*4 .. l*4+3
    const int grp = t >> 5;      // 0..7
    const int r0 = grp * 2, r1 = r0 + 1;
    const int kBase = k * NOUT;
    const int tileBase = blockIdx.x * (ROWS_IT * ITERS2);
    __syncthreads();
    for (int it = 0; it < ITERS2; ++it) {
        const int rbase = tileBase + it * ROWS_IT;
        // stage 16 gathered rows (each thread: row grp and row grp+8, float4 col l)
        {
            int pA = rbase + grp;
            int pB = pA + 8;
            float4 vA = make_float4(0.f, 0.f, 0.f, 0.f), vB = vA;
            if (pA < NOUT) { int pi = pin[kBase + pA]; vA = ((const float4*)x)[(size_t)pi * 32 + l]; }
            if (pB < NOUT) { int pi = pin[kBase + pB]; vB = ((const float4*)x)[(size_t)pi * 32 + l]; }
            xr4[grp][l] = vA;
            xr4[grp + 8][l] = vB;
        }
        __syncthreads();
        float4 acc0 = make_float4(0.f, 0.f, 0.f, 0.f), acc1 = acc0;
        const float* xa = (const float*)&xr4[r0][0];
        const float* xb = (const float*)&xr4[r1][0];
        #pragma unroll
        for (int i = 0; i < C; i += 4) {
            float4 va = *(const float4*)&xa[i];
            float4 vb = *(const float4*)&xb[i];
            float4 w0 = Wl4[(i + 0) * 32 + l];
            float4 w1 = Wl4[(i + 1) * 32 + l];
            float4 w2 = Wl4[(i + 2) * 32 + l];
            float4 w3 = Wl4[(i + 3) * 32 + l];
            fma4(acc0, va.x, w0); fma4(acc0, va.y, w1); fma4(acc0, va.z, w2); fma4(acc0, va.w, w3);
            fma4(acc1, vb.x, w0); fma4(acc1, vb.y, w1); fma4(acc1, vb.z, w2); fma4(acc1, vb.w, w3);
        }
        {
            int pa = rbase + r0;
            if (pa < NOUT) {
                int po = pout[kBase + pa];
                float* dst = &out[(size_t)po * C + l * 4];
                atomicAdd(dst + 0, acc0.x); atomicAdd(dst + 1, acc0.y);
                atomicAdd(dst + 2, acc0.z); atomicAdd(dst + 3, acc0.w);
            }
            int pb = rbase + r1;
            if (pb < NOUT) {
                int po = pout[kBase + pb];
                float* dst = &out[(size_t)po * C + l * 4];
                atomicAdd(dst + 0, acc1.x); atomicAdd(dst + 1, acc1.y);
                atomicAdd(dst + 2, acc1.z); atomicAdd(dst + 3, acc1.w);
            }
        }
        __syncthreads();
    }
}

// ---------------- per-channel sum / sumsq over rows ----------------
__global__ __launch_bounds__(256) void k_stats(const float4* __restrict__ in, float* __restrict__ stats)
{
    __shared__ float4 redS[8][32];
    __shared__ float4 redQ[8][32];
    const int t = threadIdx.x, l = t & 31, grp = t >> 5;
    const int chunk = (NOUT + gridDim.x - 1) / gridDim.x;
    const int p0 = blockIdx.x * chunk;
    const int p1 = min(p0 + chunk, NOUT);
    float4 s = make_float4(0.f, 0.f, 0.f, 0.f), q = s;
    for (int p = p0 + grp; p < p1; p += 8) {
        float4 v = in[(size_t)p * 32 + l];
        s.x += v.x; s.y += v.y; s.z += v.z; s.w += v.w;
        q.x = fmaf(v.x, v.x, q.x); q.y = fmaf(v.y, v.y, q.y);
        q.z = fmaf(v.z, v.z, q.z); q.w = fmaf(v.w, v.w, q.w);
    }
    redS[grp][l] = s; redQ[grp][l] = q;
    __syncthreads();
    if (grp == 0) {
        float4 S = redS[0][l], Q = redQ[0][l];
        #pragma unroll
        for (int g = 1; g < 8; ++g) {
            float4 a = redS[g][l], b = redQ[g][l];
            S.x += a.x; S.y += a.y; S.z += a.z; S.w += a.w;
            Q.x += b.x; Q.y += b.y; Q.z += b.z; Q.w += b.w;
        }
        atomicAdd(&stats[l * 4 + 0], S.x); atomicAdd(&stats[l * 4 + 1], S.y);
        atomicAdd(&stats[l * 4 + 2], S.z); atomicAdd(&stats[l * 4 + 3], S.w);
        atomicAdd(&stats[C + l * 4 + 0], Q.x); atomicAdd(&stats[C + l * 4 + 1], Q.y);
        atomicAdd(&stats[C + l * 4 + 2], Q.z); atomicAdd(&stats[C + l * 4 + 3], Q.w);
    }
}

// ---------------- apply BN + ReLU elementwise ----------------
__global__ __launch_bounds__(256) void k_bn_relu(const float4* __restrict__ in, float4* __restrict__ outp,
    const float* __restrict__ stats, const float* __restrict__ g, const float* __restrict__ b)
{
    __shared__ float scale[C], shift[C];
    const int t = threadIdx.x;
    if (t < C) {
        float m = stats[t] * (1.0f / NOUT);
        float var = stats[C + t] * (1.0f / NOUT) - m * m;
        float sc = g[t] * rsqrtf(var + EPSV);
        scale[t] = sc;
        shift[t] = fmaf(-m, sc, b[t]);
    }
    __syncthreads();
    const int idx0 = blockIdx.x * 256 + t;
    const int c4 = (idx0 * 4) & 127;           // invariant across grid-stride (step*4 % 128 == 0)
    const float4 sc = *(const float4*)&scale[c4];
    const float4 sh = *(const float4*)&shift[c4];
    const int total = NOUT * (C / 4);
    for (int i = idx0; i < total; i += gridDim.x * 256) {
        float4 v = in[i];
        float4 o;
        o.x = fmaxf(fmaf(v.x, sc.x, sh.x), 0.f);
        o.y = fmaxf(fmaf(v.y, sc.y, sh.y), 0.f);
        o.z = fmaxf(fmaf(v.z, sc.z, sh.z), 0.f);
        o.w = fmaxf(fmaf(v.w, sc.w, sh.w), 0.f);
        outp[i] = o;
    }
}

// ---------------- dense row GEMM (K=128), optional accumulate / stats / fused-BN-in / bias ----------------
template<bool ACCUM, bool STATS, bool BNIN, bool BIAS>
__global__ __launch_bounds__(256) void k_gemm(
    const float* __restrict__ in, const float* __restrict__ W, const float* __restrict__ bias,
    float* __restrict__ out,
    const float* __restrict__ bn_stats, const float* __restrict__ bn_g, const float* __restrict__ bn_b,
    float* __restrict__ out_stats)
{
    __shared__ float Wl[C * C];
    __shared__ float4 xr4[ROWS_IT][C / 4];
    __shared__ float scale[C], shift[C];
    __shared__ float4 redS[8][32];
    __shared__ float4 redQ[8][32];
    const int t = threadIdx.x;
    for (int i = t; i < C * C; i += 256) Wl[i] = W[i];
    if (BNIN && t < C) {
        float m = bn_stats[t] * (1.0f / NOUT);
        float var = bn_stats[C + t] * (1.0f / NOUT) - m * m;
        float sc = bn_g[t] * rsqrtf(var + EPSV);
        scale[t] = sc;
        shift[t] = fmaf(-m, sc, bn_b[t]);
    }
    __syncthreads();
    const float4* Wl4 = (const float4*)Wl;
    const int l = t & 31;
    const int grp = t >> 5;
    const int r0 = grp * 2, r1 = r0 + 1;
    float4 bias4 = make_float4(0.f, 0.f, 0.f, 0.f);
    if (BIAS) bias4 = ((const float4*)bias)[l];
    float4 scS = make_float4(0.f, 0.f, 0.f, 0.f), shS = scS;
    if (BNIN) { scS = ((const float4*)scale)[l]; shS = ((const float4*)shift)[l]; }
    float4 s4 = make_float4(0.f, 0.f, 0.f, 0.f), q4 = s4;
    const int tileBase = blockIdx.x * (ROWS_IT * ITERS_G);
    for (int it = 0; it < ITERS_G; ++it) {
        const int rbase = tileBase + it * ROWS_IT;
        {
            int pA = rbase + grp;
            int pB = pA + 8;
            float4 vA = make_float4(0.f, 0.f, 0.f, 0.f), vB = vA;
            if (pA < NOUT) vA = ((const float4*)in)[(size_t)pA * 32 + l];
            if (pB < NOUT) vB = ((const float4*)in)[(size_t)pB * 32 + l];
            if (BNIN) {
                vA.x = fmaxf(fmaf(vA.x, scS.x, shS.x), 0.f);
                vA.y = fmaxf(fmaf(vA.y, scS.y, shS.y), 0.f);
                vA.z = fmaxf(fmaf(vA.z, scS.z, shS.z), 0.f);
                vA.w = fmaxf(fmaf(vA.w, scS.w, shS.w), 0.f);
                vB.x = fmaxf(fmaf(vB.x, scS.x, shS.x), 0.f);
                vB.y = fmaxf(fmaf(vB.y, scS.y, shS.y), 0.f);
                vB.z = fmaxf(fmaf(vB.z, scS.z, shS.z), 0.f);
                vB.w = fmaxf(fmaf(vB.w, scS.w, shS.w), 0.f);
            }
            xr4[grp][l] = vA;
            xr4[grp + 8][l] = vB;
        }
        __syncthreads();
        float4 acc0 = bias4, acc1 = bias4;
        const float* xa = (const float*)&xr4[r0][0];
        const float* xb = (const float*)&xr4[r1][0];
        #pragma unroll
        for (int i = 0; i < C; i += 4) {
            float4 va = *(const float4*)&xa[i];
            float4 vb = *(const float4*)&xb[i];
            float4 w0 = Wl4[(i + 0) * 32 + l];
            float4 w1 = Wl4[(i + 1) * 32 + l];
            float4 w2 = Wl4[(i + 2) * 32 + l];
            float4 w3 = Wl4[(i + 3) * 32 + l];
            fma4(acc0, va.x, w0); fma4(acc0, va.y, w1); fma4(acc0, va.z, w2); fma4(acc0, va.w, w3);
            fma4(acc1, vb.x, w0); fma4(acc1, vb.y, w1); fma4(acc1, vb.z, w2); fma4(acc1, vb.w, w3);
        }
        {
            int pa = rbase + r0;
            if (pa < NOUT) {
                float4* dst = (float4*)&out[(size_t)pa * C + l * 4];
                float4 v = acc0;
                if (ACCUM) { float4 o = *dst; v.x += o.x; v.y += o.y; v.z += o.z; v.w += o.w; }
                *dst = v;
                if (STATS) {
                    s4.x += v.x; s4.y += v.y; s4.z += v.z; s4.w += v.w;
                    q4.x = fmaf(v.x, v.x, q4.x); q4.y = fmaf(v.y, v.y, q4.y);
                    q4.z = fmaf(v.z, v.z, q4.z); q4.w = fmaf(v.w, v.w, q4.w);
                }
            }
            int pb = rbase + r1;
            if (pb < NOUT) {
                float4* dst = (float4*)&out[(size_t)pb * C + l * 4];
                float4 v = acc1;
                if (ACCUM) { float4 o = *dst; v.x += o.x; v.y += o.y; v.z += o.z; v.w += o.w; }
                *dst = v;
                if (STATS) {
                    s4.x += v.x; s4.y += v.y; s4.z += v.z; s4.w += v.w;
                    q4.x = fmaf(v.x, v.x, q4.x); q4.y = fmaf(v.y, v.y, q4.y);
                    q4.z = fmaf(v.z, v.z, q4.z); q4.w = fmaf(v.w, v.w, q4.w);
                }
            }
        }
        __syncthreads();
    }
    if (STATS) {
        redS[grp][l] = s4; redQ[grp][l] = q4;
        __syncthreads();
        if (grp == 0) {
            float4 S = redS[0][l], Q = redQ[0][l];
            #pragma unroll
            for (int g = 1; g < 8; ++g) {
                float4 a = redS[g][l], b = redQ[g][l];
                S.x += a.x; S.y += a.y; S.z += a.z; S.w += a.w;
                Q.x += b.x; Q.y += b.y; Q.z += b.z; Q.w += b.w;
            }
            atomicAdd(&out_stats[l * 4 + 0], S.x); atomicAdd(&out_stats[l * 4 + 1], S.y);
            atomicAdd(&out_stats[l * 4 + 2], S.z); atomicAdd(&out_stats[l * 4 + 3], S.w);
            atomicAdd(&out_stats[C + l * 4 + 0], Q.x); atomicAdd(&out_stats[C + l * 4 + 1], Q.y);
            atomicAdd(&out_stats[C + l * 4 + 2], Q.z); atomicAdd(&out_stats[C + l * 4 + 3], Q.w);
        }
    }
}

// ---------------- final: out = relu(bn2(h2)) + up, in-place on d_out ----------------
__global__ __launch_bounds__(256) void k_final(float4* __restrict__ h2, const float4* __restrict__ up,
    const float* __restrict__ stats, const float* __restrict__ g, const float* __restrict__ b)
{
    __shared__ float scale[C], shift[C];
    const int t = threadIdx.x;
    if (t < C) {
        float m = stats[t] * (1.0f / NOUT);
        float var = stats[C + t] * (1.0f / NOUT) - m * m;
        float sc = g[t] * rsqrtf(var + EPSV);
        scale[t] = sc;
        shift[t] = fmaf(-m, sc, b[t]);
    }
    __syncthreads();
    const int idx0 = blockIdx.x * 256 + t;
    const int c4 = (idx0 * 4) & 127;
    const float4 sc = *(const float4*)&scale[c4];
    const float4 sh = *(const float4*)&shift[c4];
    const int total = NOUT * (C / 4);
    for (int i = idx0; i < total; i += gridDim.x * 256) {
        float4 h = h2[i];
        float4 u = up[i];
        float4 o;
        o.x = fmaxf(fmaf(h.x, sc.x, sh.x), 0.f) + u.x;
        o.y = fmaxf(fmaf(h.y, sc.y, sh.y), 0.f) + u.y;
        o.z = fmaxf(fmaf(h.z, sc.z, sh.z), 0.f) + u.z;
        o.w = fmaxf(fmaf(h.w, sc.w, sh.w), 0.f) + u.w;
        h2[i] = o;
    }
}

extern "C" void kernel_launch(void* const* d_in, const int* in_sizes, int n_in,
                              void* d_out, int out_size, void* d_ws, size_t ws_size,
                              hipStream_t stream)
{
    const float* x    = (const float*)d_in[0];
    const float* skip = (const float*)d_in[1];
    const int*   pin  = (const int*)d_in[2];
    const int*   pout = (const int*)d_in[3];
    const float* Wup  = (const float*)d_in[4];
    const float* g0   = (const float*)d_in[5];
    const float* b0   = (const float*)d_in[6];
    const float* W1   = (const float*)d_in[7];
    const float* b1   = (const float*)d_in[8];
    const float* g1   = (const float*)d_in[9];
    const float* be1  = (const float*)d_in[10];
    const float* W2   = (const float*)d_in[11];
    const float* b2   = (const float*)d_in[12];
    const float* g2   = (const float*)d_in[13];
    const float* be2  = (const float*)d_in[14];
    float* outp = (float*)d_out;

    const size_t NC = (size_t)NOUT * C;
    float* A     = (float*)d_ws;   // up_raw, later h1
    float* B     = A + NC;         // up (post BN0+ReLU)
    float* stats = B + NC;         // [0:256) BN0, [256:512) BN1, [512:768) BN2  (sum, sumsq)

    hipMemsetAsync(A, 0, NC * sizeof(float), stream);
    hipMemsetAsync(stats, 0, 6 * C * sizeof(float), stream);

    dim3 gScatter((NOUT + ROWS_IT * ITERS2 - 1) / (ROWS_IT * ITERS2), KVOL);
    k_scatter_gemm<<<gScatter, 256, 0, stream>>>(x, pin, pout, Wup, A);

    k_stats<<<512, 256, 0, stream>>>((const float4*)A, stats);
    k_bn_relu<<<1024, 256, 0, stream>>>((const float4*)A, (float4*)B, stats, g0, b0);

    const int gG = (NOUT + ROWS_IT * ITERS_G - 1) / (ROWS_IT * ITERS_G);
    // h1 = up @ W1[:128] + b1   (into A)
    k_gemm<false, false, false, true><<<gG, 256, 0, stream>>>(B, W1, b1, A,
        nullptr, nullptr, nullptr, nullptr);
    // h1 += skip @ W1[128:]; accumulate BN1 stats
    k_gemm<true, true, false, false><<<gG, 256, 0, stream>>>(skip, W1 + C * C, nullptr, A,
        nullptr, nullptr, nullptr, stats + 2 * C);
    // h2 = relu(bn1(h1)) @ W2 + b2  (into d_out); accumulate BN2 stats
    k_gemm<false, true, true, true><<<gG, 256, 0, stream>>>(A, W2, b2, outp,
        stats + 2 * C, g1, be1, stats + 4 * C);
    // d_out = relu(bn2(h2)) + up
    k_final<<<1024, 256, 0, stream>>>((float4*)outp, (const float4*)B, stats + 4 * C, g2, be2);
}

// Round 2
// 6678.188 us; speedup vs baseline: 2.3451x; 2.3451x over previous
//
#include <hip/hip_runtime.h>

#define KVOL 8
#define NIN 40000
#define NOUT 150000
#define C 128
#define EPSV 1e-5f

#define ROWS_IT 16
#define ITERS_U 16
#define ITERS_G 16
#define NPAIR (KVOL * NOUT)
#define SCAN_BLKS ((NOUT + 1 + 255) / 256)

__device__ __forceinline__ void fma4(float4& a, float s, float4 w) {
    a.x = fmaf(s, w.x, a.x);
    a.y = fmaf(s, w.y, a.y);
    a.z = fmaf(s, w.z, a.z);
    a.w = fmaf(s, w.w, a.w);
}

__device__ __forceinline__ unsigned short fbf(float f) {
    unsigned u = __float_as_uint(f);
    u += 0x7fffu + ((u >> 16) & 1u);
    return (unsigned short)(u >> 16);
}
__device__ __forceinline__ float bff(unsigned short s) {
    return __uint_as_float(((unsigned)s) << 16);
}

// ---------------- dense up GEMM: Y[k*NIN+p] = x[p] @ Wup[k]  (bf16 out) ----------------
__global__ __launch_bounds__(256) void k_up_gemm(
    const float* __restrict__ x, const float* __restrict__ Wup, ushort4* __restrict__ Y4)
{
    __shared__ float Wl[C * C];
    __shared__ float4 xr4[ROWS_IT][C / 4];
    const int t = threadIdx.x;
    const int k = blockIdx.y;
    for (int i = t; i < C * C; i += 256) Wl[i] = Wup[k * C * C + i];
    const float4* Wl4 = (const float4*)Wl;
    const int l = t & 31;
    const int grp = t >> 5;
    const int r0 = grp * 2, r1 = r0 + 1;
    const int tileBase = blockIdx.x * (ROWS_IT * ITERS_U);
    __syncthreads();
    for (int it = 0; it < ITERS_U; ++it) {
        const int rbase = tileBase + it * ROWS_IT;
        {
            int pA = rbase + grp;
            int pB = pA + 8;
            float4 vA = make_float4(0.f, 0.f, 0.f, 0.f), vB = vA;
            if (pA < NIN) vA = ((const float4*)x)[(size_t)pA * 32 + l];
            if (pB < NIN) vB = ((const float4*)x)[(size_t)pB * 32 + l];
            xr4[grp][l] = vA;
            xr4[grp + 8][l] = vB;
        }
        __syncthreads();
        float4 acc0 = make_float4(0.f, 0.f, 0.f, 0.f), acc1 = acc0;
        const float* xa = (const float*)&xr4[r0][0];
        const float* xb = (const float*)&xr4[r1][0];
        #pragma unroll
        for (int i = 0; i < C; i += 4) {
            float4 va = *(const float4*)&xa[i];
            float4 vb = *(const float4*)&xb[i];
            float4 w0 = Wl4[(i + 0) * 32 + l];
            float4 w1 = Wl4[(i + 1) * 32 + l];
            float4 w2 = Wl4[(i + 2) * 32 + l];
            float4 w3 = Wl4[(i + 3) * 32 + l];
            fma4(acc0, va.x, w0); fma4(acc0, va.y, w1); fma4(acc0, va.z, w2); fma4(acc0, va.w, w3);
            fma4(acc1, vb.x, w0); fma4(acc1, vb.y, w1); fma4(acc1, vb.z, w2); fma4(acc1, vb.w, w3);
        }
        {
            int pa = rbase + r0;
            if (pa < NIN) {
                ushort4 o;
                o.x = fbf(acc0.x); o.y = fbf(acc0.y); o.z = fbf(acc0.z); o.w = fbf(acc0.w);
                Y4[(size_t)(k * NIN + pa) * 32 + l] = o;
            }
            int pb = rbase + r1;
            if (pb < NIN) {
                ushort4 o;
                o.x = fbf(acc1.x); o.y = fbf(acc1.y); o.z = fbf(acc1.z); o.w = fbf(acc1.w);
                Y4[(size_t)(k * NIN + pb) * 32 + l] = o;
            }
        }
        __syncthreads();
    }
}

// ---------------- CSR build ----------------
__global__ __launch_bounds__(256) void k_hist(const int* __restrict__ pout, int* __restrict__ cnt)
{
    int i = blockIdx.x * 256 + threadIdx.x;
    if (i < NPAIR) atomicAdd(&cnt[pout[i]], 1);
}

__global__ __launch_bounds__(256) void k_scan1(const int* __restrict__ c, int* __restrict__ s,
                                               int* __restrict__ bs)
{
    __shared__ int sd[256];
    const int t = threadIdx.x;
    const int i = blockIdx.x * 256 + t;
    int v = (i < NOUT + 1) ? c[i] : 0;
    sd[t] = v;
    __syncthreads();
    for (int off = 1; off < 256; off <<= 1) {
        int a = sd[t];
        int b = (t >= off) ? sd[t - off] : 0;
        __syncthreads();
        sd[t] = a + b;
        __syncthreads();
    }
    if (i < NOUT + 1) s[i] = sd[t] - v;
    if (t == 255) bs[blockIdx.x] = sd[255];
}

__global__ __launch_bounds__(1024) void k_scan2(int* __restrict__ bs)
{
    __shared__ int sd[1024];
    const int t = threadIdx.x;
    int v = (t < SCAN_BLKS) ? bs[t] : 0;
    sd[t] = v;
    __syncthreads();
    for (int off = 1; off < 1024; off <<= 1) {
        int a = sd[t];
        int b = (t >= off) ? sd[t - off] : 0;
        __syncthreads();
        sd[t] = a + b;
        __syncthreads();
    }
    if (t < SCAN_BLKS) bs[t] = sd[t] - v;
}

__global__ __launch_bounds__(256) void k_scan3(int* __restrict__ s, const int* __restrict__ bs)
{
    const int i = blockIdx.x * 256 + threadIdx.x;
    if (i < NOUT + 1) s[i] += bs[blockIdx.x];
}

__global__ __launch_bounds__(256) void k_fill(const int* __restrict__ pout, const int* __restrict__ pin,
                                              int* __restrict__ cnt, const int* __restrict__ starts,
                                              int* __restrict__ entries)
{
    int i = blockIdx.x * 256 + threadIdx.x;
    if (i < NPAIR) {
        int o = pout[i];
        int old = atomicSub(&cnt[o], 1);
        int k = i / NOUT;
        entries[starts[o] + old - 1] = k * NIN + pin[i];
    }
}

// ---------------- gather-reduce: up_raw[o] = sum Y[rid]; fused BN0 stats ----------------
__global__ __launch_bounds__(256) void k_gather(
    const ushort4* __restrict__ Y4, const int* __restrict__ starts, const int* __restrict__ entries,
    float4* __restrict__ outr, float* __restrict__ stats)
{
    __shared__ float4 redS[8][32];
    __shared__ float4 redQ[8][32];
    const int t = threadIdx.x, l = t & 31, grp = t >> 5;
    float4 s4 = make_float4(0.f, 0.f, 0.f, 0.f), q4 = s4;
    const int base = blockIdx.x * 256;
    for (int it = 0; it < 32; ++it) {
        int o = base + it * 8 + grp;
        if (o < NOUT) {
            int s0 = starts[o], s1 = starts[o + 1];
            float4 acc = make_float4(0.f, 0.f, 0.f, 0.f);
            for (int j = s0; j < s1; ++j) {
                int rid = entries[j];
                ushort4 u = Y4[(size_t)rid * 32 + l];
                acc.x += bff(u.x); acc.y += bff(u.y);
                acc.z += bff(u.z); acc.w += bff(u.w);
            }
            outr[(size_t)o * 32 + l] = acc;
            s4.x += acc.x; s4.y += acc.y; s4.z += acc.z; s4.w += acc.w;
            q4.x = fmaf(acc.x, acc.x, q4.x); q4.y = fmaf(acc.y, acc.y, q4.y);
            q4.z = fmaf(acc.z, acc.z, q4.z); q4.w = fmaf(acc.w, acc.w, q4.w);
        }
    }
    redS[grp][l] = s4; redQ[grp][l] = q4;
    __syncthreads();
    if (grp == 0) {
        float4 S = redS[0][l], Q = redQ[0][l];
        #pragma unroll
        for (int g = 1; g < 8; ++g) {
            float4 a = redS[g][l], b = redQ[g][l];
            S.x += a.x; S.y += a.y; S.z += a.z; S.w += a.w;
            Q.x += b.x; Q.y += b.y; Q.z += b.z; Q.w += b.w;
        }
        atomicAdd(&stats[l * 4 + 0], S.x); atomicAdd(&stats[l * 4 + 1], S.y);
        atomicAdd(&stats[l * 4 + 2], S.z); atomicAdd(&stats[l * 4 + 3], S.w);
        atomicAdd(&stats[C + l * 4 + 0], Q.x); atomicAdd(&stats[C + l * 4 + 1], Q.y);
        atomicAdd(&stats[C + l * 4 + 2], Q.z); atomicAdd(&stats[C + l * 4 + 3], Q.w);
    }
}

// ---------------- apply BN + ReLU elementwise (in-place safe) ----------------
__global__ __launch_bounds__(256) void k_bn_relu(const float4* __restrict__ in, float4* __restrict__ outp,
    const float* __restrict__ stats, const float* __restrict__ g, const float* __restrict__ b)
{
    __shared__ float scale[C], shift[C];
    const int t = threadIdx.x;
    if (t < C) {
        float m = stats[t] * (1.0f / NOUT);
        float var = stats[C + t] * (1.0f / NOUT) - m * m;
        float sc = g[t] * rsqrtf(var + EPSV);
        scale[t] = sc;
        shift[t] = fmaf(-m, sc, b[t]);
    }
    __syncthreads();
    const int idx0 = blockIdx.x * 256 + t;
    const int c4 = (idx0 * 4) & 127;
    const float4 sc = *(const float4*)&scale[c4];
    const float4 sh = *(const float4*)&shift[c4];
    const int total = NOUT * (C / 4);
    for (int i = idx0; i < total; i += gridDim.x * 256) {
        float4 v = in[i];
        float4 o;
        o.x = fmaxf(fmaf(v.x, sc.x, sh.x), 0.f);
        o.y = fmaxf(fmaf(v.y, sc.y, sh.y), 0.f);
        o.z = fmaxf(fmaf(v.z, sc.z, sh.z), 0.f);
        o.w = fmaxf(fmaf(v.w, sc.w, sh.w), 0.f);
        outp[i] = o;
    }
}

// ---------------- dense row GEMM (K=128), optional accumulate / stats / fused-BN-in / bias ----------------
template<bool ACCUM, bool STATS, bool BNIN, bool BIAS>
__global__ __launch_bounds__(256) void k_gemm(
    const float* __restrict__ in, const float* __restrict__ W, const float* __restrict__ bias,
    float* __restrict__ out,
    const float* __restrict__ bn_stats, const float* __restrict__ bn_g, const float* __restrict__ bn_b,
    float* __restrict__ out_stats)
{
    __shared__ float Wl[C * C];
    __shared__ float4 xr4[ROWS_IT][C / 4];
    __shared__ float scale[C], shift[C];
    __shared__ float4 redS[8][32];
    __shared__ float4 redQ[8][32];
    const int t = threadIdx.x;
    for (int i = t; i < C * C; i += 256) Wl[i] = W[i];
    if (BNIN && t < C) {
        float m = bn_stats[t] * (1.0f / NOUT);
        float var = bn_stats[C + t] * (1.0f / NOUT) - m * m;
        float sc = bn_g[t] * rsqrtf(var + EPSV);
        scale[t] = sc;
        shift[t] = fmaf(-m, sc, bn_b[t]);
    }
    __syncthreads();
    const float4* Wl4 = (const float4*)Wl;
    const int l = t & 31;
    const int grp = t >> 5;
    const int r0 = grp * 2, r1 = r0 + 1;
    float4 bias4 = make_float4(0.f, 0.f, 0.f, 0.f);
    if (BIAS) bias4 = ((const float4*)bias)[l];
    float4 scS = make_float4(0.f, 0.f, 0.f, 0.f), shS = scS;
    if (BNIN) { scS = ((const float4*)scale)[l]; shS = ((const float4*)shift)[l]; }
    float4 s4 = make_float4(0.f, 0.f, 0.f, 0.f), q4 = s4;
    const int tileBase = blockIdx.x * (ROWS_IT * ITERS_G);
    for (int it = 0; it < ITERS_G; ++it) {
        const int rbase = tileBase + it * ROWS_IT;
        {
            int pA = rbase + grp;
            int pB = pA + 8;
            float4 vA = make_float4(0.f, 0.f, 0.f, 0.f), vB = vA;
            if (pA < NOUT) vA = ((const float4*)in)[(size_t)pA * 32 + l];
            if (pB < NOUT) vB = ((const float4*)in)[(size_t)pB * 32 + l];
            if (BNIN) {
                vA.x = fmaxf(fmaf(vA.x, scS.x, shS.x), 0.f);
                vA.y = fmaxf(fmaf(vA.y, scS.y, shS.y), 0.f);
                vA.z = fmaxf(fmaf(vA.z, scS.z, shS.z), 0.f);
                vA.w = fmaxf(fmaf(vA.w, scS.w, shS.w), 0.f);
                vB.x = fmaxf(fmaf(vB.x, scS.x, shS.x), 0.f);
                vB.y = fmaxf(fmaf(vB.y, scS.y, shS.y), 0.f);
                vB.z = fmaxf(fmaf(vB.z, scS.z, shS.z), 0.f);
                vB.w = fmaxf(fmaf(vB.w, scS.w, shS.w), 0.f);
            }
            xr4[grp][l] = vA;
            xr4[grp + 8][l] = vB;
        }
        __syncthreads();
        float4 acc0 = bias4, acc1 = bias4;
        const float* xa = (const float*)&xr4[r0][0];
        const float* xb = (const float*)&xr4[r1][0];
        #pragma unroll
        for (int i = 0; i < C; i += 4) {
            float4 va = *(const float4*)&xa[i];
            float4 vb = *(const float4*)&xb[i];
            float4 w0 = Wl4[(i + 0) * 32 + l];
            float4 w1 = Wl4[(i + 1) * 32 + l];
            float4 w2 = Wl4[(i + 2) * 32 + l];
            float4 w3 = Wl4[(i + 3) * 32 + l];
            fma4(acc0, va.x, w0); fma4(acc0, va.y, w1); fma4(acc0, va.z, w2); fma4(acc0, va.w, w3);
            fma4(acc1, vb.x, w0); fma4(acc1, vb.y, w1); fma4(acc1, vb.z, w2); fma4(acc1, vb.w, w3);
        }
        {
            int pa = rbase + r0;
            if (pa < NOUT) {
                float4* dst = (float4*)&out[(size_t)pa * C + l * 4];
                float4 v = acc0;
                if (ACCUM) { float4 o = *dst; v.x += o.x; v.y += o.y; v.z += o.z; v.w += o.w; }
                *dst = v;
                if (STATS) {
                    s4.x += v.x; s4.y += v.y; s4.z += v.z; s4.w += v.w;
                    q4.x = fmaf(v.x, v.x, q4.x); q4.y = fmaf(v.y, v.y, q4.y);
                    q4.z = fmaf(v.z, v.z, q4.z); q4.w = fmaf(v.w, v.w, q4.w);
                }
            }
            int pb = rbase + r1;
            if (pb < NOUT) {
                float4* dst = (float4*)&out[(size_t)pb * C + l * 4];
                float4 v = acc1;
                if (ACCUM) { float4 o = *dst; v.x += o.x; v.y += o.y; v.z += o.z; v.w += o.w; }
                *dst = v;
                if (STATS) {
                    s4.x += v.x; s4.y += v.y; s4.z += v.z; s4.w += v.w;
                    q4.x = fmaf(v.x, v.x, q4.x); q4.y = fmaf(v.y, v.y, q4.y);
                    q4.z = fmaf(v.z, v.z, q4.z); q4.w = fmaf(v.w, v.w, q4.w);
                }
            }
        }
        __syncthreads();
    }
    if (STATS) {
        redS[grp][l] = s4; redQ[grp][l] = q4;
        __syncthreads();
        if (grp == 0) {
            float4 S = redS[0][l], Q = redQ[0][l];
            #pragma unroll
            for (int g = 1; g < 8; ++g) {
                float4 a = redS[g][l], b = redQ[g][l];
                S.x += a.x; S.y += a.y; S.z += a.z; S.w += a.w;
                Q.x += b.x; Q.y += b.y; Q.z += b.z; Q.w += b.w;
            }
            atomicAdd(&out_stats[l * 4 + 0], S.x); atomicAdd(&out_stats[l * 4 + 1], S.y);
            atomicAdd(&out_stats[l * 4 + 2], S.z); atomicAdd(&out_stats[l * 4 + 3], S.w);
            atomicAdd(&out_stats[C + l * 4 + 0], Q.x); atomicAdd(&out_stats[C + l * 4 + 1], Q.y);
            atomicAdd(&out_stats[C + l * 4 + 2], Q.z); atomicAdd(&out_stats[C + l * 4 + 3], Q.w);
        }
    }
}

// ---------------- final: out = relu(bn2(h2)) + up, in-place on d_out ----------------
__global__ __launch_bounds__(256) void k_final(const float4* __restrict__ h2, float4* __restrict__ up_io,
    const float* __restrict__ stats, const float* __restrict__ g, const float* __restrict__ b)
{
    __shared__ float scale[C], shift[C];
    const int t = threadIdx.x;
    if (t < C) {
        float m = stats[t] * (1.0f / NOUT);
        float var = stats[C + t] * (1.0f / NOUT) - m * m;
        float sc = g[t] * rsqrtf(var + EPSV);
        scale[t] = sc;
        shift[t] = fmaf(-m, sc, b[t]);
    }
    __syncthreads();
    const int idx0 = blockIdx.x * 256 + t;
    const int c4 = (idx0 * 4) & 127;
    const float4 sc = *(const float4*)&scale[c4];
    const float4 sh = *(const float4*)&shift[c4];
    const int total = NOUT * (C / 4);
    for (int i = idx0; i < total; i += gridDim.x * 256) {
        float4 h = h2[i];
        float4 u = up_io[i];
        float4 o;
        o.x = fmaxf(fmaf(h.x, sc.x, sh.x), 0.f) + u.x;
        o.y = fmaxf(fmaf(h.y, sc.y, sh.y), 0.f) + u.y;
        o.z = fmaxf(fmaf(h.z, sc.z, sh.z), 0.f) + u.z;
        o.w = fmaxf(fmaf(h.w, sc.w, sh.w), 0.f) + u.w;
        up_io[i] = o;
    }
}

extern "C" void kernel_launch(void* const* d_in, const int* in_sizes, int n_in,
                              void* d_out, int out_size, void* d_ws, size_t ws_size,
                              hipStream_t stream)
{
    const float* x    = (const float*)d_in[0];
    const float* skip = (const float*)d_in[1];
    const int*   pin  = (const int*)d_in[2];
    const int*   pout = (const int*)d_in[3];
    const float* Wup  = (const float*)d_in[4];
    const float* g0   = (const float*)d_in[5];
    const float* b0   = (const float*)d_in[6];
    const float* W1   = (const float*)d_in[7];
    const float* b1   = (const float*)d_in[8];
    const float* g1   = (const float*)d_in[9];
    const float* be1  = (const float*)d_in[10];
    const float* W2   = (const float*)d_in[11];
    const float* b2   = (const float*)d_in[12];
    const float* g2   = (const float*)d_in[13];
    const float* be2  = (const float*)d_in[14];
    float* outp = (float*)d_out;

    // ws layout
    const size_t Y_BYTES  = (size_t)KVOL * NIN * C * sizeof(ushort);   // 81,920,000
    const size_t NC_BYTES = (size_t)NOUT * C * sizeof(float);          // 76,800,000
    char* base = (char*)d_ws;
    ushort4* Y4  = (ushort4*)base;            // Y (bf16), dead after k_gather
    float*   h2  = (float*)base;              // aliases Y region (used after Y dead)
    float*   h1  = (float*)(base + Y_BYTES);
    char* p = base + Y_BYTES + NC_BYTES;
    int* counts    = (int*)p; p += (size_t)(NOUT + 4) * sizeof(int);
    int* starts    = (int*)p; p += (size_t)(NOUT + 4) * sizeof(int);
    int* entries   = (int*)p; p += (size_t)NPAIR * sizeof(int);
    int* blockSums = (int*)p; p += 4096;
    float* stats   = (float*)p;               // [0:2C) BN0, [2C:4C) BN1, [4C:6C) BN2

    hipMemsetAsync(counts, 0, (size_t)(NOUT + 4) * sizeof(int), stream);
    hipMemsetAsync(stats, 0, 6 * C * sizeof(float), stream);

    // 1. Y[k] = x @ Wup[k]  (bf16 out)
    dim3 gUp((NIN + ROWS_IT * ITERS_U - 1) / (ROWS_IT * ITERS_U), KVOL);
    k_up_gemm<<<gUp, 256, 0, stream>>>(x, Wup, Y4);

    // 2. CSR build of pout
    const int gPair = (NPAIR + 255) / 256;
    k_hist<<<gPair, 256, 0, stream>>>(pout, counts);
    k_scan1<<<SCAN_BLKS, 256, 0, stream>>>(counts, starts, blockSums);
    k_scan2<<<1, 1024, 0, stream>>>(blockSums);
    k_scan3<<<SCAN_BLKS, 256, 0, stream>>>(starts, blockSums);
    k_fill<<<gPair, 256, 0, stream>>>(pout, pin, counts, starts, entries);

    // 3. gather-reduce -> up_raw (in d_out), fused BN0 stats
    k_gather<<<(NOUT + 255) / 256, 256, 0, stream>>>(Y4, starts, entries, (float4*)outp, stats);

    // 4. up = relu(bn0(up_raw)) in-place in d_out
    k_bn_relu<<<1024, 256, 0, stream>>>((const float4*)outp, (float4*)outp, stats, g0, b0);

    const int gG = (NOUT + ROWS_IT * ITERS_G - 1) / (ROWS_IT * ITERS_G);
    // 5. h1 = up @ W1[:128] + b1
    k_gemm<false, false, false, true><<<gG, 256, 0, stream>>>(outp, W1, b1, h1,
        nullptr, nullptr, nullptr, nullptr);
    // 6. h1 += skip @ W1[128:]; BN1 stats
    k_gemm<true, true, false, false><<<gG, 256, 0, stream>>>(skip, W1 + C * C, nullptr, h1,
        nullptr, nullptr, nullptr, stats + 2 * C);
    // 7. h2 = relu(bn1(h1)) @ W2 + b2; BN2 stats
    k_gemm<false, true, true, true><<<gG, 256, 0, stream>>>(h1, W2, b2, h2,
        stats + 2 * C, g1, be1, stats + 4 * C);
    // 8. d_out = relu(bn2(h2)) + up
    k_final<<<1024, 256, 0, stream>>>((const float4*)h2, (float4*)outp, stats + 4 * C, g2, be2);
}

// Round 3
// 736.391 us; speedup vs baseline: 21.2673x; 9.0688x over previous
//
#include <hip/hip_runtime.h>

#define KVOL 8
#define NIN 40000
#define NOUT 150000
#define C 128
#define EPSV 1e-5f
#define NPAIR (KVOL * NOUT)
#define SCAN_BLKS ((NOUT + 1 + 255) / 256)
#define GM ((NOUT + 63) / 64)          // 2344 blocks for M=150000
#define GUP (NIN / 64)                 // 625 blocks for M=40000
#define GATH ((NOUT + 255) / 256)      // 586

typedef __attribute__((ext_vector_type(8))) __bf16 bf16x8;
typedef __attribute__((ext_vector_type(4))) float f32x4;

__device__ __forceinline__ unsigned short fbf(float f) {
    unsigned u = __float_as_uint(f);
    u += 0x7fffu + ((u >> 16) & 1u);
    return (unsigned short)(u >> 16);
}
__device__ __forceinline__ float bff(unsigned short s) {
    return __uint_as_float(((unsigned)s) << 16);
}

// =============== MFMA GEMM: out[M,128](bf16) = sum_ph A_ph[M,128] @ W[ph*128.., 128] =============
// A fragment: m = lane&15, k = kk*32 + (lane>>4)*8 + i   (same map for B -> k-permutation cancels)
// C/D fragment (verified): col = lane&15, row = (lane>>4)*4 + reg
template<int PHASES, bool A0F32, bool A1F32, bool BNIN, bool BIAS, bool STATS>
__global__ __launch_bounds__(256) void k_mfma(
    const void* __restrict__ A0v, const void* __restrict__ A1v,
    const float* __restrict__ Wsrc, size_t wStrideK,
    const float* __restrict__ bias,
    unsigned short* __restrict__ outp, size_t oStrideK,
    int M,
    const float* __restrict__ bn_stats, const float* __restrict__ bn_g, const float* __restrict__ bn_b,
    float* __restrict__ parts)
{
    __shared__ __align__(16) unsigned short Alds[64][136];
    __shared__ __align__(16) unsigned short Wlds[128][136];
    __shared__ float4 sscale4[32];
    __shared__ float4 sshift4[32];
    __shared__ float sbuf[256];
    const int t = threadIdx.x;
    const int wave = t >> 6, lane = t & 63;
    const int l15 = lane & 15, lhi = lane >> 4;
    const int R = blockIdx.x * 64;
    const float* Wp0 = Wsrc + (size_t)blockIdx.y * wStrideK;
    unsigned short* outk = outp + (size_t)blockIdx.y * oStrideK;

    if (BNIN) {
        if (t < C) {
            float m = bn_stats[t] * (1.0f / NOUT);
            float var = bn_stats[C + t] * (1.0f / NOUT) - m * m;
            float sc = bn_g[t] * rsqrtf(var + EPSV);
            ((float*)sscale4)[t] = sc;
            ((float*)sshift4)[t] = fmaf(-m, sc, bn_b[t]);
        }
        __syncthreads();
    }
    if (STATS) sbuf[t] = 0.0f;

    f32x4 acc[8];
    #pragma unroll
    for (int n = 0; n < 8; ++n) acc[n] = (f32x4){0.f, 0.f, 0.f, 0.f};

    #pragma unroll
    for (int ph = 0; ph < PHASES; ++ph) {
        const void* Ap = (ph == 0) ? A0v : A1v;
        const bool AF32 = (ph == 0) ? A0F32 : A1F32;
        const float* Wp = Wp0 + (size_t)ph * (C * C);
        // stage W^T as bf16: Wlds[n][k] = W[k][n]
        for (int idx = t; idx < C * C; idx += 256) {
            int k = idx >> 7, n = idx & 127;
            Wlds[n][k] = fbf(Wp[idx]);   // Wp[idx] == Wp[k*128+n]
        }
        // stage A tile [64][128] as bf16
        if (AF32) {
            const float4* A4 = (const float4*)Ap;
            #pragma unroll
            for (int j = 0; j < 8; ++j) {
                int idx = t + j * 256;           // 0..2047 float4 slots
                int row = idx >> 5, c4 = idx & 31;
                int grow = R + row;
                float4 v = make_float4(0.f, 0.f, 0.f, 0.f);
                if (grow < M) v = A4[(size_t)grow * 32 + c4];
                ushort4 o;
                o.x = fbf(v.x); o.y = fbf(v.y); o.z = fbf(v.z); o.w = fbf(v.w);
                *(ushort4*)&Alds[row][c4 * 4] = o;
            }
        } else {
            const ushort4* A4 = (const ushort4*)Ap;
            #pragma unroll
            for (int j = 0; j < 8; ++j) {
                int idx = t + j * 256;
                int row = idx >> 5, c4 = idx & 31;
                int grow = R + row;
                ushort4 v = make_ushort4(0, 0, 0, 0);
                if (grow < M) v = A4[(size_t)grow * 32 + c4];
                if (BNIN) {
                    float4 sc = sscale4[c4], sh = sshift4[c4];
                    float f0 = fmaxf(fmaf(bff(v.x), sc.x, sh.x), 0.f);
                    float f1 = fmaxf(fmaf(bff(v.y), sc.y, sh.y), 0.f);
                    float f2 = fmaxf(fmaf(bff(v.z), sc.z, sh.z), 0.f);
                    float f3 = fmaxf(fmaf(bff(v.w), sc.w, sh.w), 0.f);
                    v.x = fbf(f0); v.y = fbf(f1); v.z = fbf(f2); v.w = fbf(f3);
                }
                *(ushort4*)&Alds[row][c4 * 4] = v;
            }
        }
        __syncthreads();
        // compute: wave owns rows [wave*16, wave*16+16), all 128 cols
        bf16x8 af[4];
        #pragma unroll
        for (int kk = 0; kk < 4; ++kk)
            af[kk] = *(const bf16x8*)&Alds[wave * 16 + l15][kk * 32 + lhi * 8];
        #pragma unroll
        for (int n = 0; n < 8; ++n) {
            #pragma unroll
            for (int kk = 0; kk < 4; ++kk) {
                bf16x8 bfr = *(const bf16x8*)&Wlds[n * 16 + l15][kk * 32 + lhi * 8];
                acc[n] = __builtin_amdgcn_mfma_f32_16x16x32_bf16(af[kk], bfr, acc[n], 0, 0, 0);
            }
        }
        __syncthreads();
    }
    // epilogue: bias, store bf16, stats partials
    #pragma unroll
    for (int n = 0; n < 8; ++n) {
        const int col = n * 16 + l15;
        float bv = BIAS ? bias[col] : 0.0f;
        float s = 0.f, q = 0.f;
        #pragma unroll
        for (int r = 0; r < 4; ++r) {
            int row = R + wave * 16 + lhi * 4 + r;
            if (row < M) {
                float v = acc[n][r] + bv;
                outk[(size_t)row * C + col] = fbf(v);
                if (STATS) { s += v; q = fmaf(v, v, q); }
            }
        }
        if (STATS) {
            atomicAdd(&sbuf[col], s);
            atomicAdd(&sbuf[C + col], q);
        }
    }
    if (STATS) {
        __syncthreads();
        parts[(size_t)blockIdx.x * 256 + t] = sbuf[t];
    }
}

// =============== stats partial reduction: stats[t] += sum_b parts[b][t] (stats pre-zeroed) =======
__global__ __launch_bounds__(256) void k_reduce(const float* __restrict__ parts, int nb,
                                                float* __restrict__ stats)
{
    const int t = threadIdx.x;
    float s0 = 0.f, s1 = 0.f, s2 = 0.f, s3 = 0.f;
    for (int b = blockIdx.x * 4; b < nb; b += gridDim.x * 4) {
        if (b < nb)     s0 += parts[(size_t)b * 256 + t];
        if (b + 1 < nb) s1 += parts[(size_t)(b + 1) * 256 + t];
        if (b + 2 < nb) s2 += parts[(size_t)(b + 2) * 256 + t];
        if (b + 3 < nb) s3 += parts[(size_t)(b + 3) * 256 + t];
    }
    atomicAdd(&stats[t], (s0 + s1) + (s2 + s3));
}

// =============== CSR build ===============
__global__ __launch_bounds__(256) void k_hist(const int* __restrict__ pout, int* __restrict__ cnt)
{
    int i = blockIdx.x * 256 + threadIdx.x;
    if (i < NPAIR) atomicAdd(&cnt[pout[i]], 1);
}

__global__ __launch_bounds__(256) void k_scan1(const int* __restrict__ c, int* __restrict__ s,
                                               int* __restrict__ bs)
{
    __shared__ int sd[256];
    const int t = threadIdx.x;
    const int i = blockIdx.x * 256 + t;
    int v = (i < NOUT + 1) ? c[i] : 0;
    sd[t] = v;
    __syncthreads();
    for (int off = 1; off < 256; off <<= 1) {
        int a = sd[t];
        int b = (t >= off) ? sd[t - off] : 0;
        __syncthreads();
        sd[t] = a + b;
        __syncthreads();
    }
    if (i < NOUT + 1) s[i] = sd[t] - v;
    if (t == 255) bs[blockIdx.x] = sd[255];
}

__global__ __launch_bounds__(1024) void k_scan2(int* __restrict__ bs)
{
    __shared__ int sd[1024];
    const int t = threadIdx.x;
    int v = (t < SCAN_BLKS) ? bs[t] : 0;
    sd[t] = v;
    __syncthreads();
    for (int off = 1; off < 1024; off <<= 1) {
        int a = sd[t];
        int b = (t >= off) ? sd[t - off] : 0;
        __syncthreads();
        sd[t] = a + b;
        __syncthreads();
    }
    if (t < SCAN_BLKS) bs[t] = sd[t] - v;
}

__global__ __launch_bounds__(256) void k_scan3(int* __restrict__ s, const int* __restrict__ bs)
{
    const int i = blockIdx.x * 256 + threadIdx.x;
    if (i < NOUT + 1) s[i] += bs[blockIdx.x];
}

__global__ __launch_bounds__(256) void k_fill(const int* __restrict__ pout, const int* __restrict__ pin,
                                              int* __restrict__ cnt, const int* __restrict__ starts,
                                              int* __restrict__ entries)
{
    int i = blockIdx.x * 256 + threadIdx.x;
    if (i < NPAIR) {
        int o = pout[i];
        int old = atomicSub(&cnt[o], 1);
        int k = i / NOUT;
        entries[starts[o] + old - 1] = k * NIN + pin[i];
    }
}

// =============== gather-reduce: up_raw[o] = sum Y[rid]; BN0 stats partials ===============
__global__ __launch_bounds__(256) void k_gather(
    const ushort4* __restrict__ Y4, const int* __restrict__ starts, const int* __restrict__ entries,
    float4* __restrict__ outr, float* __restrict__ parts)
{
    __shared__ float4 redS[8][32];
    __shared__ float4 redQ[8][32];
    const int t = threadIdx.x, l = t & 31, grp = t >> 5;
    float4 s4 = make_float4(0.f, 0.f, 0.f, 0.f), q4 = s4;
    const int base = blockIdx.x * 256;
    for (int it = 0; it < 32; ++it) {
        int o = base + it * 8 + grp;
        if (o < NOUT) {
            int s0 = starts[o], s1 = starts[o + 1];
            float4 acc = make_float4(0.f, 0.f, 0.f, 0.f);
            for (int j = s0; j < s1; ++j) {
                int rid = entries[j];
                ushort4 u = Y4[(size_t)rid * 32 + l];
                acc.x += bff(u.x); acc.y += bff(u.y);
                acc.z += bff(u.z); acc.w += bff(u.w);
            }
            outr[(size_t)o * 32 + l] = acc;
            s4.x += acc.x; s4.y += acc.y; s4.z += acc.z; s4.w += acc.w;
            q4.x = fmaf(acc.x, acc.x, q4.x); q4.y = fmaf(acc.y, acc.y, q4.y);
            q4.z = fmaf(acc.z, acc.z, q4.z); q4.w = fmaf(acc.w, acc.w, q4.w);
        }
    }
    redS[grp][l] = s4; redQ[grp][l] = q4;
    __syncthreads();
    if (grp == 0) {
        float4 S = redS[0][l], Q = redQ[0][l];
        #pragma unroll
        for (int g = 1; g < 8; ++g) {
            float4 a = redS[g][l], b = redQ[g][l];
            S.x += a.x; S.y += a.y; S.z += a.z; S.w += a.w;
            Q.x += b.x; Q.y += b.y; Q.z += b.z; Q.w += b.w;
        }
        *(float4*)&parts[(size_t)blockIdx.x * 256 + l * 4] = S;
        *(float4*)&parts[(size_t)blockIdx.x * 256 + C + l * 4] = Q;
    }
}

// =============== BN0 + ReLU, fp32 in-place ===============
__global__ __launch_bounds__(256) void k_bn_relu(const float4* __restrict__ in, float4* __restrict__ outp,
    const float* __restrict__ stats, const float* __restrict__ g, const float* __restrict__ b)
{
    __shared__ float scale[C], shift[C];
    const int t = threadIdx.x;
    if (t < C) {
        float m = stats[t] * (1.0f / NOUT);
        float var = stats[C + t] * (1.0f / NOUT) - m * m;
        float sc = g[t] * rsqrtf(var + EPSV);
        scale[t] = sc;
        shift[t] = fmaf(-m, sc, b[t]);
    }
    __syncthreads();
    const int idx0 = blockIdx.x * 256 + t;
    const int c4 = (idx0 * 4) & 127;
    const float4 sc = *(const float4*)&scale[c4];
    const float4 sh = *(const float4*)&shift[c4];
    const int total = NOUT * (C / 4);
    for (int i = idx0; i < total; i += gridDim.x * 256) {
        float4 v = in[i];
        float4 o;
        o.x = fmaxf(fmaf(v.x, sc.x, sh.x), 0.f);
        o.y = fmaxf(fmaf(v.y, sc.y, sh.y), 0.f);
        o.z = fmaxf(fmaf(v.z, sc.z, sh.z), 0.f);
        o.w = fmaxf(fmaf(v.w, sc.w, sh.w), 0.f);
        outp[i] = o;
    }
}

// =============== final: out = relu(bn2(h2_bf16)) + up, in-place on d_out ===============
__global__ __launch_bounds__(256) void k_final(const ushort4* __restrict__ h2, float4* __restrict__ up_io,
    const float* __restrict__ stats, const float* __restrict__ g, const float* __restrict__ b)
{
    __shared__ float scale[C], shift[C];
    const int t = threadIdx.x;
    if (t < C) {
        float m = stats[t] * (1.0f / NOUT);
        float var = stats[C + t] * (1.0f / NOUT) - m * m;
        float sc = g[t] * rsqrtf(var + EPSV);
        scale[t] = sc;
        shift[t] = fmaf(-m, sc, b[t]);
    }
    __syncthreads();
    const int idx0 = blockIdx.x * 256 + t;
    const int c4 = (idx0 * 4) & 127;
    const float4 sc = *(const float4*)&scale[c4];
    const float4 sh = *(const float4*)&shift[c4];
    const int total = NOUT * (C / 4);
    for (int i = idx0; i < total; i += gridDim.x * 256) {
        ushort4 h = h2[i];
        float4 u = up_io[i];
        float4 o;
        o.x = fmaxf(fmaf(bff(h.x), sc.x, sh.x), 0.f) + u.x;
        o.y = fmaxf(fmaf(bff(h.y), sc.y, sh.y), 0.f) + u.y;
        o.z = fmaxf(fmaf(bff(h.z), sc.z, sh.z), 0.f) + u.z;
        o.w = fmaxf(fmaf(bff(h.w), sc.w, sh.w), 0.f) + u.w;
        up_io[i] = o;
    }
}

extern "C" void kernel_launch(void* const* d_in, const int* in_sizes, int n_in,
                              void* d_out, int out_size, void* d_ws, size_t ws_size,
                              hipStream_t stream)
{
    const float* x    = (const float*)d_in[0];
    const float* skip = (const float*)d_in[1];
    const int*   pin  = (const int*)d_in[2];
    const int*   pout = (const int*)d_in[3];
    const float* Wup  = (const float*)d_in[4];
    const float* g0   = (const float*)d_in[5];
    const float* b0   = (const float*)d_in[6];
    const float* W1   = (const float*)d_in[7];
    const float* b1   = (const float*)d_in[8];
    const float* g1   = (const float*)d_in[9];
    const float* be1  = (const float*)d_in[10];
    const float* W2   = (const float*)d_in[11];
    const float* b2   = (const float*)d_in[12];
    const float* g2   = (const float*)d_in[13];
    const float* be2  = (const float*)d_in[14];
    float* outp = (float*)d_out;

    // ws layout (Y region reused by h1/h2 after gather)
    char* base = (char*)d_ws;
    unsigned short* Y  = (unsigned short*)base;                 // 8*40000*128*2 = 81,920,000 B
    unsigned short* h1 = (unsigned short*)base;                 // alias: live after Y dead
    unsigned short* h2 = (unsigned short*)(base + 40960000);    // alias: no overlap with h1
    char* p = base + 81920000;
    int* counts    = (int*)p; p += (size_t)(NOUT + 4) * 4;
    int* starts    = (int*)p; p += (size_t)(NOUT + 4) * 4;
    int* entries   = (int*)p; p += (size_t)NPAIR * 4;
    int* blockSums = (int*)p; p += 4096;
    float* parts0  = (float*)p; p += (size_t)GATH * 256 * 4;
    float* parts1  = (float*)p; p += (size_t)GM * 256 * 4;
    float* parts2  = (float*)p; p += (size_t)GM * 256 * 4;
    float* stats   = (float*)p; p += 3 * 256 * 4;               // stats0 | stats1 | stats2

    hipMemsetAsync(counts, 0, (size_t)(NOUT + 4) * 4, stream);
    hipMemsetAsync(stats, 0, 3 * 256 * 4, stream);

    // 1. Y[k] = x @ Wup[k]  (bf16, MFMA)
    k_mfma<1, true, true, false, false, false><<<dim3(GUP, KVOL), 256, 0, stream>>>(
        x, nullptr, Wup, (size_t)C * C, nullptr, Y, (size_t)NIN * C, NIN,
        nullptr, nullptr, nullptr, nullptr);

    // 2. CSR build of pout
    const int gPair = (NPAIR + 255) / 256;
    k_hist<<<gPair, 256, 0, stream>>>(pout, counts);
    k_scan1<<<SCAN_BLKS, 256, 0, stream>>>(counts, starts, blockSums);
    k_scan2<<<1, 1024, 0, stream>>>(blockSums);
    k_scan3<<<SCAN_BLKS, 256, 0, stream>>>(starts, blockSums);
    k_fill<<<gPair, 256, 0, stream>>>(pout, pin, counts, starts, entries);

    // 3. gather-reduce -> up_raw fp32 (d_out) + BN0 stats partials
    k_gather<<<GATH, 256, 0, stream>>>((const ushort4*)Y, starts, entries, (float4*)outp, parts0);
    k_reduce<<<16, 256, 0, stream>>>(parts0, GATH, stats);

    // 4. up = relu(bn0(up_raw)) in-place in d_out (fp32)
    k_bn_relu<<<1024, 256, 0, stream>>>((const float4*)outp, (float4*)outp, stats, g0, b0);

    // 5. h1 = bf16( up @ W1[:128] + skip @ W1[128:] + b1 ) + BN1 stats partials
    k_mfma<2, true, true, false, true, true><<<GM, 256, 0, stream>>>(
        outp, skip, W1, 0, b1, h1, 0, NOUT, nullptr, nullptr, nullptr, parts1);
    k_reduce<<<16, 256, 0, stream>>>(parts1, GM, stats + 256);

    // 6. h2 = bf16( relu(bn1(h1)) @ W2 + b2 ) + BN2 stats partials
    k_mfma<1, false, false, true, true, true><<<GM, 256, 0, stream>>>(
        h1, nullptr, W2, 0, b2, h2, 0, NOUT, stats + 256, g1, be1, parts2);
    k_reduce<<<16, 256, 0, stream>>>(parts2, GM, stats + 512);

    // 7. d_out = relu(bn2(h2)) + up
    k_final<<<1024, 256, 0, stream>>>((const ushort4*)h2, (float4*)outp, stats + 512, g2, be2);
}

// Round 4
// 552.496 us; speedup vs baseline: 28.3460x; 1.3328x over previous
//
#include <hip/hip_runtime.h>

#define KVOL 8
#define NIN 40000
#define NOUT 150000
#define C 128
#define EPSV 1e-5f
#define NPAIR (KVOL * NOUT)
#define SCAN_BLKS ((NOUT + 1 + 255) / 256)
#define GM ((NOUT + 63) / 64)          // 2344
#define GUP (NIN / 64)                 // 625
#define GATH ((NOUT + 63) / 64)       // 2344

typedef __attribute__((ext_vector_type(8))) __bf16 bf16x8;
typedef __attribute__((ext_vector_type(4))) float f32x4;
typedef __attribute__((ext_vector_type(8))) unsigned short us8;

__device__ __forceinline__ unsigned short fbf(float f) {
    unsigned u = __float_as_uint(f);
    u += 0x7fffu + ((u >> 16) & 1u);
    return (unsigned short)(u >> 16);
}
__device__ __forceinline__ float bff(unsigned short s) {
    return __uint_as_float(((unsigned)s) << 16);
}

// =============== weight prep: WT[b][n][k] = bf16(W_b[k][n]), b in {Wup0..7, W1a, W1b, W2} =======
__global__ __launch_bounds__(256) void k_prep_w(
    const float* __restrict__ Wup, const float* __restrict__ W1, const float* __restrict__ W2,
    unsigned short* __restrict__ WT)
{
    int i = blockIdx.x * 256 + threadIdx.x;
    if (i < 11 * 16384) {
        int b = i >> 14, r = i & 16383;
        int k = r >> 7, n = r & 127;
        const float* src = (b < 8) ? (Wup + (size_t)b * 16384)
                         : (b < 10) ? (W1 + (size_t)(b - 8) * 16384) : W2;
        WT[(size_t)b * 16384 + n * 128 + k] = fbf(src[k * 128 + n]);
    }
}

// =============== up GEMM: Y[k] = x @ Wup[k] (bf16 out); A staged once, loop k ===============
// A frag: m = lane&15, k = kk*32 + (lane>>4)*8 + i (same map both operands -> permutation cancels)
// C/D frag: col = lane&15, row = (lane>>4)*4 + reg
__global__ __launch_bounds__(256) void k_up(
    const float* __restrict__ x, const unsigned short* __restrict__ WT,
    unsigned short* __restrict__ Y)
{
    __shared__ __align__(16) unsigned short Alds[64][136];
    __shared__ __align__(16) unsigned short Wlds[128][136];
    const int t = threadIdx.x;
    const int wave = t >> 6, lane = t & 63;
    const int l15 = lane & 15, lhi = lane >> 4;
    const int R = blockIdx.x * 64;
    const float4* A4 = (const float4*)x;
    #pragma unroll
    for (int j = 0; j < 8; ++j) {
        int idx = t + j * 256;
        int row = idx >> 5, c4 = idx & 31;
        int grow = R + row;
        float4 v = make_float4(0.f, 0.f, 0.f, 0.f);
        if (grow < NIN) v = A4[(size_t)grow * 32 + c4];
        ushort4 o;
        o.x = fbf(v.x); o.y = fbf(v.y); o.z = fbf(v.z); o.w = fbf(v.w);
        *(ushort4*)&Alds[row][c4 * 4] = o;
    }
    __syncthreads();
    bf16x8 af[4];
    #pragma unroll
    for (int kk = 0; kk < 4; ++kk)
        af[kk] = *(const bf16x8*)&Alds[wave * 16 + l15][kk * 32 + lhi * 8];
    for (int k = 0; k < KVOL; ++k) {
        __syncthreads();
        const us8* Wsrc = (const us8*)(WT + (size_t)k * C * C);
        #pragma unroll
        for (int j = 0; j < 8; ++j) {
            int slot = t + j * 256;
            int n = slot >> 4, koff = (slot & 15) * 8;
            *(us8*)&Wlds[n][koff] = Wsrc[slot];
        }
        __syncthreads();
        f32x4 acc[8];
        #pragma unroll
        for (int n = 0; n < 8; ++n) acc[n] = (f32x4){0.f, 0.f, 0.f, 0.f};
        #pragma unroll
        for (int n = 0; n < 8; ++n) {
            #pragma unroll
            for (int kk = 0; kk < 4; ++kk) {
                bf16x8 bfr = *(const bf16x8*)&Wlds[n * 16 + l15][kk * 32 + lhi * 8];
                acc[n] = __builtin_amdgcn_mfma_f32_16x16x32_bf16(af[kk], bfr, acc[n], 0, 0, 0);
            }
        }
        unsigned short* Yk = Y + (size_t)k * NIN * C;
        #pragma unroll
        for (int n = 0; n < 8; ++n) {
            const int col = n * 16 + l15;
            #pragma unroll
            for (int r = 0; r < 4; ++r) {
                int row = R + wave * 16 + lhi * 4 + r;
                if (row < NIN) Yk[(size_t)row * C + col] = fbf(acc[n][r]);
            }
        }
    }
}

// =============== main MFMA GEMM: out = bf16( sum_ph A_ph @ W_ph + bias ), optional BN-in ph0 ====
template<int PHASES, bool A0F32, bool A1F32, bool BNIN, bool STATS>
__global__ __launch_bounds__(256) void k_mfma(
    const void* __restrict__ A0v, const void* __restrict__ A1v,
    const unsigned short* __restrict__ WT,
    const float* __restrict__ bias,
    unsigned short* __restrict__ outp, int M,
    const float* __restrict__ bn_stats, const float* __restrict__ bn_g, const float* __restrict__ bn_b,
    float* __restrict__ parts)
{
    __shared__ __align__(16) unsigned short Alds[64][136];
    __shared__ __align__(16) unsigned short Wlds[128][136];
    __shared__ float sscale[C], sshift[C];
    __shared__ float sbuf[256];
    const int t = threadIdx.x;
    const int wave = t >> 6, lane = t & 63;
    const int l15 = lane & 15, lhi = lane >> 4;
    const int R = blockIdx.x * 64;

    if (BNIN) {
        if (t < C) {
            float m = bn_stats[t] * (1.0f / NOUT);
            float var = bn_stats[C + t] * (1.0f / NOUT) - m * m;
            float sc = bn_g[t] * rsqrtf(var + EPSV);
            sscale[t] = sc;
            sshift[t] = fmaf(-m, sc, bn_b[t]);
        }
        __syncthreads();
    }
    if (STATS) sbuf[t] = 0.0f;

    f32x4 acc[8];
    #pragma unroll
    for (int n = 0; n < 8; ++n) acc[n] = (f32x4){0.f, 0.f, 0.f, 0.f};

    #pragma unroll
    for (int ph = 0; ph < PHASES; ++ph) {
        const void* Ap = (ph == 0) ? A0v : A1v;
        const bool AF32 = (ph == 0) ? A0F32 : A1F32;
        const us8* Wsrc = (const us8*)(WT + (size_t)ph * C * C);
        #pragma unroll
        for (int j = 0; j < 8; ++j) {
            int slot = t + j * 256;
            int n = slot >> 4, koff = (slot & 15) * 8;
            *(us8*)&Wlds[n][koff] = Wsrc[slot];
        }
        if (AF32) {
            const float4* A4 = (const float4*)Ap;
            #pragma unroll
            for (int j = 0; j < 8; ++j) {
                int idx = t + j * 256;
                int row = idx >> 5, c4 = idx & 31;
                int grow = R + row;
                float4 v = make_float4(0.f, 0.f, 0.f, 0.f);
                if (grow < M) v = A4[(size_t)grow * 32 + c4];
                ushort4 o;
                o.x = fbf(v.x); o.y = fbf(v.y); o.z = fbf(v.z); o.w = fbf(v.w);
                *(ushort4*)&Alds[row][c4 * 4] = o;
            }
        } else {
            const us8* A8 = (const us8*)Ap;
            #pragma unroll
            for (int j = 0; j < 4; ++j) {
                int slot = t + j * 256;
                int row = slot >> 4, s15 = slot & 15;
                int koff = s15 * 8;
                int grow = R + row;
                us8 v = {0, 0, 0, 0, 0, 0, 0, 0};
                if (grow < M) v = A8[(size_t)grow * 16 + s15];
                if (BNIN && ph == 0) {
                    us8 w;
                    #pragma unroll
                    for (int i = 0; i < 8; ++i) {
                        float f = fmaxf(fmaf(bff(v[i]), sscale[koff + i], sshift[koff + i]), 0.f);
                        w[i] = fbf(f);
                    }
                    v = w;
                }
                *(us8*)&Alds[row][koff] = v;
            }
        }
        __syncthreads();
        bf16x8 af[4];
        #pragma unroll
        for (int kk = 0; kk < 4; ++kk)
            af[kk] = *(const bf16x8*)&Alds[wave * 16 + l15][kk * 32 + lhi * 8];
        #pragma unroll
        for (int n = 0; n < 8; ++n) {
            #pragma unroll
            for (int kk = 0; kk < 4; ++kk) {
                bf16x8 bfr = *(const bf16x8*)&Wlds[n * 16 + l15][kk * 32 + lhi * 8];
                acc[n] = __builtin_amdgcn_mfma_f32_16x16x32_bf16(af[kk], bfr, acc[n], 0, 0, 0);
            }
        }
        __syncthreads();
    }
    #pragma unroll
    for (int n = 0; n < 8; ++n) {
        const int col = n * 16 + l15;
        float bv = bias[col];
        float s = 0.f, q = 0.f;
        #pragma unroll
        for (int r = 0; r < 4; ++r) {
            int row = R + wave * 16 + lhi * 4 + r;
            if (row < M) {
                float v = acc[n][r] + bv;
                outp[(size_t)row * C + col] = fbf(v);
                if (STATS) { s += v; q = fmaf(v, v, q); }
            }
        }
        if (STATS) {
            atomicAdd(&sbuf[col], s);
            atomicAdd(&sbuf[C + col], q);
        }
    }
    if (STATS) {
        __syncthreads();
        parts[(size_t)blockIdx.x * 256 + t] = sbuf[t];
    }
}

// =============== stats partial reduction ===============
__global__ __launch_bounds__(256) void k_reduce(const float* __restrict__ parts, int nb,
                                                float* __restrict__ stats)
{
    const int t = threadIdx.x;
    float s0 = 0.f, s1 = 0.f, s2 = 0.f, s3 = 0.f;
    for (int b = blockIdx.x * 4; b < nb; b += gridDim.x * 4) {
        if (b < nb)     s0 += parts[(size_t)b * 256 + t];
        if (b + 1 < nb) s1 += parts[(size_t)(b + 1) * 256 + t];
        if (b + 2 < nb) s2 += parts[(size_t)(b + 2) * 256 + t];
        if (b + 3 < nb) s3 += parts[(size_t)(b + 3) * 256 + t];
    }
    atomicAdd(&stats[t], (s0 + s1) + (s2 + s3));
}

// =============== CSR build ===============
__global__ __launch_bounds__(256) void k_hist(const int* __restrict__ pout, int* __restrict__ cnt)
{
    int i = blockIdx.x * 256 + threadIdx.x;
    if (i < NPAIR) atomicAdd(&cnt[pout[i]], 1);
}

__global__ __launch_bounds__(256) void k_scan1(const int* __restrict__ c, int* __restrict__ s,
                                               int* __restrict__ bs)
{
    __shared__ int sd[256];
    const int t = threadIdx.x;
    const int i = blockIdx.x * 256 + t;
    int v = (i < NOUT + 1) ? c[i] : 0;
    sd[t] = v;
    __syncthreads();
    for (int off = 1; off < 256; off <<= 1) {
        int a = sd[t];
        int b = (t >= off) ? sd[t - off] : 0;
        __syncthreads();
        sd[t] = a + b;
        __syncthreads();
    }
    if (i < NOUT + 1) s[i] = sd[t] - v;
    if (t == 255) bs[blockIdx.x] = sd[255];
}

__global__ __launch_bounds__(1024) void k_scan2(int* __restrict__ bs)
{
    __shared__ int sd[1024];
    const int t = threadIdx.x;
    int v = (t < SCAN_BLKS) ? bs[t] : 0;
    sd[t] = v;
    __syncthreads();
    for (int off = 1; off < 1024; off <<= 1) {
        int a = sd[t];
        int b = (t >= off) ? sd[t - off] : 0;
        __syncthreads();
        sd[t] = a + b;
        __syncthreads();
    }
    if (t < SCAN_BLKS) bs[t] = sd[t] - v;
}

__global__ __launch_bounds__(256) void k_scan3(int* __restrict__ s, const int* __restrict__ bs)
{
    const int i = blockIdx.x * 256 + threadIdx.x;
    if (i < NOUT + 1) s[i] += bs[blockIdx.x];
}

__global__ __launch_bounds__(256) void k_fill(const int* __restrict__ pout, const int* __restrict__ pin,
                                              int* __restrict__ cnt, const int* __restrict__ starts,
                                              int* __restrict__ entries)
{
    int i = blockIdx.x * 256 + threadIdx.x;
    if (i < NPAIR) {
        int o = pout[i];
        int old = atomicSub(&cnt[o], 1);
        int k = i / NOUT;
        entries[starts[o] + old - 1] = k * NIN + pin[i];
    }
}

// =============== gather-reduce: up_raw[o] (bf16) = sum Y[rid]; BN0 stats partials ===============
// 64 rows/block, 16 lanes/row (us8 = 8 channels each), 2-entry unrolled
__global__ __launch_bounds__(256) void k_gather(
    const us8* __restrict__ Y8, const int* __restrict__ starts, const int* __restrict__ entries,
    us8* __restrict__ up8, float* __restrict__ parts)
{
    __shared__ float sS[16][16][8];
    __shared__ float sQ[16][16][8];
    const int t = threadIdx.x;
    const int rl = t >> 4, c8 = t & 15;
    float s[8], q[8];
    #pragma unroll
    for (int i = 0; i < 8; ++i) { s[i] = 0.f; q[i] = 0.f; }
    const int base = blockIdx.x * 64;
    #pragma unroll
    for (int it = 0; it < 4; ++it) {
        int o = base + it * 16 + rl;
        if (o < NOUT) {
            int j0 = starts[o], j1 = starts[o + 1];
            float a[8];
            #pragma unroll
            for (int i = 0; i < 8; ++i) a[i] = 0.f;
            int j = j0;
            for (; j + 1 < j1; j += 2) {
                int e0 = entries[j], e1 = entries[j + 1];
                us8 u0 = Y8[(size_t)e0 * 16 + c8];
                us8 u1 = Y8[(size_t)e1 * 16 + c8];
                #pragma unroll
                for (int i = 0; i < 8; ++i) a[i] += bff(u0[i]) + bff(u1[i]);
            }
            if (j < j1) {
                int e0 = entries[j];
                us8 u0 = Y8[(size_t)e0 * 16 + c8];
                #pragma unroll
                for (int i = 0; i < 8; ++i) a[i] += bff(u0[i]);
            }
            us8 o8;
            #pragma unroll
            for (int i = 0; i < 8; ++i) {
                o8[i] = fbf(a[i]);
                s[i] += a[i];
                q[i] = fmaf(a[i], a[i], q[i]);
            }
            up8[(size_t)o * 16 + c8] = o8;
        }
    }
    #pragma unroll
    for (int i = 0; i < 8; ++i) { sS[rl][c8][i] = s[i]; sQ[rl][c8][i] = q[i]; }
    __syncthreads();
    if (t < 128) {
        const int cc = t >> 3, ii = t & 7;
        float S = 0.f, Q = 0.f;
        #pragma unroll
        for (int r = 0; r < 16; ++r) { S += sS[r][cc][ii]; Q += sQ[r][cc][ii]; }
        parts[(size_t)blockIdx.x * 256 + t] = S;
        parts[(size_t)blockIdx.x * 256 + 128 + t] = Q;
    }
}

// =============== final: out = relu(bn2(h2)) + relu(bn0(up_raw)), fp32 out ===============
__global__ __launch_bounds__(256) void k_final(
    const us8* __restrict__ h2, const us8* __restrict__ upr, float* __restrict__ out,
    const float* __restrict__ stats2, const float* __restrict__ g2, const float* __restrict__ be2,
    const float* __restrict__ stats0, const float* __restrict__ g0, const float* __restrict__ b0)
{
    __shared__ float sc2[C], sh2[C], sc0[C], sh0[C];
    const int t = threadIdx.x;
    if (t < C) {
        float m2 = stats2[t] * (1.0f / NOUT);
        float v2 = stats2[C + t] * (1.0f / NOUT) - m2 * m2;
        float c2 = g2[t] * rsqrtf(v2 + EPSV);
        sc2[t] = c2; sh2[t] = fmaf(-m2, c2, be2[t]);
        float m0 = stats0[t] * (1.0f / NOUT);
        float v0 = stats0[C + t] * (1.0f / NOUT) - m0 * m0;
        float c0 = g0[t] * rsqrtf(v0 + EPSV);
        sc0[t] = c0; sh0[t] = fmaf(-m0, c0, b0[t]);
    }
    __syncthreads();
    const int idx0 = blockIdx.x * 256 + t;
    const int c8 = idx0 & 15;           // invariant: step = grid*256 is multiple of 16
    float l2s[8], l2h[8], l0s[8], l0h[8];
    #pragma unroll
    for (int i = 0; i < 8; ++i) {
        l2s[i] = sc2[c8 * 8 + i]; l2h[i] = sh2[c8 * 8 + i];
        l0s[i] = sc0[c8 * 8 + i]; l0h[i] = sh0[c8 * 8 + i];
    }
    const int total = NOUT * 16;
    for (int idx = idx0; idx < total; idx += gridDim.x * 256) {
        us8 h = h2[idx];
        us8 u = upr[idx];
        float o[8];
        #pragma unroll
        for (int i = 0; i < 8; ++i) {
            o[i] = fmaxf(fmaf(bff(h[i]), l2s[i], l2h[i]), 0.f)
                 + fmaxf(fmaf(bff(u[i]), l0s[i], l0h[i]), 0.f);
        }
        float4* dst = (float4*)&out[(size_t)idx * 8];
        dst[0] = make_float4(o[0], o[1], o[2], o[3]);
        dst[1] = make_float4(o[4], o[5], o[6], o[7]);
    }
}

extern "C" void kernel_launch(void* const* d_in, const int* in_sizes, int n_in,
                              void* d_out, int out_size, void* d_ws, size_t ws_size,
                              hipStream_t stream)
{
    const float* x    = (const float*)d_in[0];
    const float* skip = (const float*)d_in[1];
    const int*   pin  = (const int*)d_in[2];
    const int*   pout = (const int*)d_in[3];
    const float* Wup  = (const float*)d_in[4];
    const float* g0   = (const float*)d_in[5];
    const float* b0   = (const float*)d_in[6];
    const float* W1   = (const float*)d_in[7];
    const float* b1   = (const float*)d_in[8];
    const float* g1   = (const float*)d_in[9];
    const float* be1  = (const float*)d_in[10];
    const float* W2   = (const float*)d_in[11];
    const float* b2   = (const float*)d_in[12];
    const float* g2   = (const float*)d_in[13];
    const float* be2  = (const float*)d_in[14];
    float* outp = (float*)d_out;

    // ws layout: Y (82MB) reused by h1/h2 after gather; up_raw separate
    char* base = (char*)d_ws;
    unsigned short* Y      = (unsigned short*)base;               // 81,920,000 B
    unsigned short* h1     = (unsigned short*)base;               // alias (Y dead)
    unsigned short* h2     = (unsigned short*)(base + 40960000);  // alias (no overlap with h1)
    unsigned short* up_raw = (unsigned short*)(base + 81920000);  // 38,400,000 B
    char* p = base + 81920000 + 38400000;
    unsigned short* WT = (unsigned short*)p; p += (size_t)11 * 16384 * 2;
    int* counts    = (int*)p; p += (size_t)(NOUT + 4) * 4;
    int* starts    = (int*)p; p += (size_t)(NOUT + 4) * 4;
    int* entries   = (int*)p; p += (size_t)NPAIR * 4;
    int* blockSums = (int*)p; p += 4096;
    float* parts0  = (float*)p; p += (size_t)GATH * 256 * 4;
    float* parts1  = (float*)p; p += (size_t)GM * 256 * 4;
    float* parts2  = (float*)p; p += (size_t)GM * 256 * 4;
    float* stats   = (float*)p; p += 3 * 256 * 4;   // stats0 | stats1 | stats2

    hipMemsetAsync(counts, 0, (size_t)(NOUT + 4) * 4, stream);
    hipMemsetAsync(stats, 0, 3 * 256 * 4, stream);

    // 0. weights -> bf16 transposed
    k_prep_w<<<(11 * 16384 + 255) / 256, 256, 0, stream>>>(Wup, W1, W2, WT);

    // 1. Y[k] = x @ Wup[k]
    k_up<<<GUP, 256, 0, stream>>>(x, WT, Y);

    // 2. CSR build of pout
    const int gPair = (NPAIR + 255) / 256;
    k_hist<<<gPair, 256, 0, stream>>>(pout, counts);
    k_scan1<<<SCAN_BLKS, 256, 0, stream>>>(counts, starts, blockSums);
    k_scan2<<<1, 1024, 0, stream>>>(blockSums);
    k_scan3<<<SCAN_BLKS, 256, 0, stream>>>(starts, blockSums);
    k_fill<<<gPair, 256, 0, stream>>>(pout, pin, counts, starts, entries);

    // 3. gather-reduce -> up_raw bf16 + BN0 stats
    k_gather<<<GATH, 256, 0, stream>>>((const us8*)Y, starts, entries, (us8*)up_raw, parts0);
    k_reduce<<<16, 256, 0, stream>>>(parts0, GATH, stats);

    // 4. h1 = bf16( relu(bn0(up_raw)) @ W1[:128] + skip @ W1[128:] + b1 ) + BN1 stats
    k_mfma<2, false, true, true, true><<<GM, 256, 0, stream>>>(
        up_raw, skip, WT + (size_t)8 * 16384, b1, h1, NOUT, stats, g0, b0, parts1);
    k_reduce<<<16, 256, 0, stream>>>(parts1, GM, stats + 256);

    // 5. h2 = bf16( relu(bn1(h1)) @ W2 + b2 ) + BN2 stats
    k_mfma<1, false, false, true, true><<<GM, 256, 0, stream>>>(
        h1, nullptr, WT + (size_t)10 * 16384, b2, h2, NOUT, stats + 256, g1, be1, parts2);
    k_reduce<<<16, 256, 0, stream>>>(parts2, GM, stats + 512);

    // 6. out = relu(bn2(h2)) + relu(bn0(up_raw))
    k_final<<<1024, 256, 0, stream>>>((const us8*)h2, (const us8*)up_raw, outp,
        stats + 512, g2, be2, stats, g0, b0);
}

// Round 5
// 415.149 us; speedup vs baseline: 37.7238x; 1.3308x over previous
//
#include <hip/hip_runtime.h>

#define KVOL 8
#define NIN 40000
#define NOUT 150000
#define C 128
#define EPSV 1e-5f
#define NPAIR (KVOL * NOUT)
#define SCAN_BLKS ((NOUT + 1 + 255) / 256)
#define GM ((NOUT + 63) / 64)          // 2344 (parts sizing)
#define GM2 ((NOUT + 127) / 128)       // 1172 (128-row MFMA tiles)
#define GUP (NIN / 64)                 // 625
#define GATH ((NOUT + 63) / 64)        // 2344

typedef __attribute__((ext_vector_type(8))) __bf16 bf16x8;
typedef __attribute__((ext_vector_type(4))) float f32x4;
typedef __attribute__((ext_vector_type(8))) unsigned short us8;

__device__ __forceinline__ unsigned short fbf(float f) {
    unsigned u = __float_as_uint(f);
    u += 0x7fffu + ((u >> 16) & 1u);
    return (unsigned short)(u >> 16);
}
__device__ __forceinline__ float bff(unsigned short s) {
    return __uint_as_float(((unsigned)s) << 16);
}

// =============== weight prep: WT[b][n][k] = bf16(W_b[k][n]), b in {Wup0..7, W1a, W1b, W2} =======
__global__ __launch_bounds__(256) void k_prep_w(
    const float* __restrict__ Wup, const float* __restrict__ W1, const float* __restrict__ W2,
    unsigned short* __restrict__ WT)
{
    int i = blockIdx.x * 256 + threadIdx.x;
    if (i < 11 * 16384) {
        int b = i >> 14, r = i & 16383;
        int k = r >> 7, n = r & 127;
        const float* src = (b < 8) ? (Wup + (size_t)b * 16384)
                         : (b < 10) ? (W1 + (size_t)(b - 8) * 16384) : W2;
        WT[(size_t)b * 16384 + n * 128 + k] = fbf(src[k * 128 + n]);
    }
}

// =============== up GEMM: Y[k] = x @ Wup[k] (bf16 out); A staged once, loop k ===============
// A frag: m = lane&15, k = kk*32 + (lane>>4)*8 + i (same map both operands -> permutation cancels)
// C/D frag: col = lane&15, row = (lane>>4)*4 + reg
__global__ __launch_bounds__(256) void k_up(
    const float* __restrict__ x, const unsigned short* __restrict__ WT,
    unsigned short* __restrict__ Y)
{
    __shared__ __align__(16) unsigned short Alds[64][136];
    __shared__ __align__(16) unsigned short Wlds[128][136];
    const int t = threadIdx.x;
    const int wave = t >> 6, lane = t & 63;
    const int l15 = lane & 15, lhi = lane >> 4;
    const int R = blockIdx.x * 64;
    const float4* A4 = (const float4*)x;
    #pragma unroll
    for (int j = 0; j < 8; ++j) {
        int idx = t + j * 256;
        int row = idx >> 5, c4 = idx & 31;
        int grow = R + row;
        float4 v = make_float4(0.f, 0.f, 0.f, 0.f);
        if (grow < NIN) v = A4[(size_t)grow * 32 + c4];
        ushort4 o;
        o.x = fbf(v.x); o.y = fbf(v.y); o.z = fbf(v.z); o.w = fbf(v.w);
        *(ushort4*)&Alds[row][c4 * 4] = o;
    }
    __syncthreads();
    bf16x8 af[4];
    #pragma unroll
    for (int kk = 0; kk < 4; ++kk)
        af[kk] = *(const bf16x8*)&Alds[wave * 16 + l15][kk * 32 + lhi * 8];
    for (int k = 0; k < KVOL; ++k) {
        __syncthreads();
        const us8* Wsrc = (const us8*)(WT + (size_t)k * C * C);
        #pragma unroll
        for (int j = 0; j < 8; ++j) {
            int slot = t + j * 256;
            int n = slot >> 4, koff = (slot & 15) * 8;
            *(us8*)&Wlds[n][koff] = Wsrc[slot];
        }
        __syncthreads();
        f32x4 acc[8];
        #pragma unroll
        for (int n = 0; n < 8; ++n) acc[n] = (f32x4){0.f, 0.f, 0.f, 0.f};
        #pragma unroll
        for (int n = 0; n < 8; ++n) {
            #pragma unroll
            for (int kk = 0; kk < 4; ++kk) {
                bf16x8 bfr = *(const bf16x8*)&Wlds[n * 16 + l15][kk * 32 + lhi * 8];
                acc[n] = __builtin_amdgcn_mfma_f32_16x16x32_bf16(af[kk], bfr, acc[n], 0, 0, 0);
            }
        }
        unsigned short* Yk = Y + (size_t)k * NIN * C;
        #pragma unroll
        for (int n = 0; n < 8; ++n) {
            const int col = n * 16 + l15;
            #pragma unroll
            for (int r = 0; r < 4; ++r) {
                int row = R + wave * 16 + lhi * 4 + r;
                if (row < NIN) Yk[(size_t)row * C + col] = fbf(acc[n][r]);
            }
        }
    }
}

// =============== main MFMA GEMM (128x128 tile, 512 thr): out = bf16( sum_ph A_ph @ W_ph + b ) ====
// A0 always bf16 (+ optional fused BN-ReLU); A1 (PHASES==2) always fp32, prefetched in regs.
template<int PHASES, bool BNIN, bool STATS>
__global__ __launch_bounds__(512) void k_mfma(
    const void* __restrict__ A0v, const void* __restrict__ A1v,
    const unsigned short* __restrict__ WT,
    const float* __restrict__ bias,
    unsigned short* __restrict__ outp, int M,
    const float* __restrict__ bn_stats, const float* __restrict__ bn_g, const float* __restrict__ bn_b,
    float* __restrict__ parts)
{
    __shared__ __align__(16) unsigned short Alds[128][136];
    __shared__ __align__(16) unsigned short Wlds[128][136];
    __shared__ float sscale[C], sshift[C];
    const int t = threadIdx.x;
    const int wave = t >> 6, lane = t & 63;
    const int l15 = lane & 15, lhi = lane >> 4;
    const int R = blockIdx.x * 128;

    if (BNIN) {
        if (t < C) {
            float m = bn_stats[t] * (1.0f / NOUT);
            float var = bn_stats[C + t] * (1.0f / NOUT) - m * m;
            float sc = bn_g[t] * rsqrtf(var + EPSV);
            sscale[t] = sc;
            sshift[t] = fmaf(-m, sc, bn_b[t]);
        }
        __syncthreads();
    }

    f32x4 acc[8];
    #pragma unroll
    for (int n = 0; n < 8; ++n) acc[n] = (f32x4){0.f, 0.f, 0.f, 0.f};

    // ---- stage phase 0: W (bf16 linear copy) + A0 (bf16, optional BN+ReLU) ----
    {
        const us8* Wsrc = (const us8*)WT;
        #pragma unroll
        for (int j = 0; j < 4; ++j) {
            int slot = t + j * 512;
            *(us8*)&Wlds[slot >> 4][(slot & 15) * 8] = Wsrc[slot];
        }
        const us8* A8 = (const us8*)A0v;
        #pragma unroll
        for (int j = 0; j < 4; ++j) {
            int slot = t + j * 512;
            int row = slot >> 4, s15 = slot & 15, koff = s15 * 8;
            int grow = R + row;
            us8 v = (us8){0, 0, 0, 0, 0, 0, 0, 0};
            if (grow < M) v = A8[(size_t)grow * 16 + s15];
            if (BNIN) {
                us8 w;
                #pragma unroll
                for (int i = 0; i < 8; ++i) {
                    float f = fmaxf(fmaf(bff(v[i]), sscale[koff + i], sshift[koff + i]), 0.f);
                    w[i] = fbf(f);
                }
                v = w;
            }
            *(us8*)&Alds[row][koff] = v;
        }
    }
    __syncthreads();

    if constexpr (PHASES == 2) {
        // prefetch phase 1 (W1b + fp32 A1) into registers while phase 0 computes
        us8 wreg[4];
        float4 areg[8];
        {
            const us8* Wsrc1 = (const us8*)(WT + C * C);
            #pragma unroll
            for (int j = 0; j < 4; ++j) wreg[j] = Wsrc1[t + j * 512];
            const float4* A41 = (const float4*)A1v;
            #pragma unroll
            for (int j = 0; j < 8; ++j) {
                int slot = t + j * 512;
                int row = slot >> 5, c4 = slot & 31;
                int grow = R + row;
                float4 v = make_float4(0.f, 0.f, 0.f, 0.f);
                if (grow < M) v = A41[(size_t)grow * 32 + c4];
                areg[j] = v;
            }
        }
        // compute phase 0
        {
            bf16x8 af[4];
            #pragma unroll
            for (int kk = 0; kk < 4; ++kk)
                af[kk] = *(const bf16x8*)&Alds[wave * 16 + l15][kk * 32 + lhi * 8];
            #pragma unroll
            for (int n = 0; n < 8; ++n) {
                #pragma unroll
                for (int kk = 0; kk < 4; ++kk) {
                    bf16x8 bfr = *(const bf16x8*)&Wlds[n * 16 + l15][kk * 32 + lhi * 8];
                    acc[n] = __builtin_amdgcn_mfma_f32_16x16x32_bf16(af[kk], bfr, acc[n], 0, 0, 0);
                }
            }
        }
        __syncthreads();
        // write phase 1 staging from registers
        #pragma unroll
        for (int j = 0; j < 4; ++j) {
            int slot = t + j * 512;
            *(us8*)&Wlds[slot >> 4][(slot & 15) * 8] = wreg[j];
        }
        #pragma unroll
        for (int j = 0; j < 8; ++j) {
            int slot = t + j * 512;
            int row = slot >> 5, c4 = slot & 31;
            float4 v = areg[j];
            ushort4 o;
            o.x = fbf(v.x); o.y = fbf(v.y); o.z = fbf(v.z); o.w = fbf(v.w);
            *(ushort4*)&Alds[row][c4 * 4] = o;
        }
        __syncthreads();
    }
    // compute last phase
    {
        bf16x8 af[4];
        #pragma unroll
        for (int kk = 0; kk < 4; ++kk)
            af[kk] = *(const bf16x8*)&Alds[wave * 16 + l15][kk * 32 + lhi * 8];
        #pragma unroll
        for (int n = 0; n < 8; ++n) {
            #pragma unroll
            for (int kk = 0; kk < 4; ++kk) {
                bf16x8 bfr = *(const bf16x8*)&Wlds[n * 16 + l15][kk * 32 + lhi * 8];
                acc[n] = __builtin_amdgcn_mfma_f32_16x16x32_bf16(af[kk], bfr, acc[n], 0, 0, 0);
            }
        }
    }
    __syncthreads();   // Alds/Wlds dead; safe to reuse Alds for stats

    float* sbS = (float*)&Alds[0][0];       // [8][128]
    float* sbQ = sbS + 1024;                // [8][128]
    #pragma unroll
    for (int n = 0; n < 8; ++n) {
        const int col = n * 16 + l15;
        float bv = bias[col];
        float s = 0.f, q = 0.f;
        #pragma unroll
        for (int r = 0; r < 4; ++r) {
            int row = R + wave * 16 + lhi * 4 + r;
            if (row < M) {
                float v = acc[n][r] + bv;
                outp[(size_t)row * C + col] = fbf(v);
                if (STATS) { s += v; q = fmaf(v, v, q); }
            }
        }
        if (STATS) {
            s += __shfl_xor(s, 16); s += __shfl_xor(s, 32);
            q += __shfl_xor(q, 16); q += __shfl_xor(q, 32);
            if (lane < 16) {
                sbS[wave * 128 + col] = s;
                sbQ[wave * 128 + col] = q;
            }
        }
    }
    if (STATS) {
        __syncthreads();
        if (t < 128) {
            float S = 0.f;
            #pragma unroll
            for (int w = 0; w < 8; ++w) S += sbS[w * 128 + t];
            parts[(size_t)blockIdx.x * 256 + t] = S;
        } else if (t < 256) {
            int cc = t - 128;
            float Q = 0.f;
            #pragma unroll
            for (int w = 0; w < 8; ++w) Q += sbQ[w * 128 + cc];
            parts[(size_t)blockIdx.x * 256 + t] = Q;
        }
    }
}

// =============== stats partial reduction ===============
__global__ __launch_bounds__(256) void k_reduce(const float* __restrict__ parts, int nb,
                                                float* __restrict__ stats)
{
    const int t = threadIdx.x;
    float s0 = 0.f, s1 = 0.f, s2 = 0.f, s3 = 0.f;
    for (int b = blockIdx.x * 4; b < nb; b += gridDim.x * 4) {
        if (b < nb)     s0 += parts[(size_t)b * 256 + t];
        if (b + 1 < nb) s1 += parts[(size_t)(b + 1) * 256 + t];
        if (b + 2 < nb) s2 += parts[(size_t)(b + 2) * 256 + t];
        if (b + 3 < nb) s3 += parts[(size_t)(b + 3) * 256 + t];
    }
    atomicAdd(&stats[t], (s0 + s1) + (s2 + s3));
}

// =============== CSR build ===============
__global__ __launch_bounds__(256) void k_hist(const int* __restrict__ pout, int* __restrict__ cnt)
{
    int i = blockIdx.x * 256 + threadIdx.x;
    if (i < NPAIR) atomicAdd(&cnt[pout[i]], 1);
}

__global__ __launch_bounds__(256) void k_scan1(const int* __restrict__ c, int* __restrict__ s,
                                               int* __restrict__ bs)
{
    __shared__ int sd[256];
    const int t = threadIdx.x;
    const int i = blockIdx.x * 256 + t;
    int v = (i < NOUT + 1) ? c[i] : 0;
    sd[t] = v;
    __syncthreads();
    for (int off = 1; off < 256; off <<= 1) {
        int a = sd[t];
        int b = (t >= off) ? sd[t - off] : 0;
        __syncthreads();
        sd[t] = a + b;
        __syncthreads();
    }
    if (i < NOUT + 1) s[i] = sd[t] - v;
    if (t == 255) bs[blockIdx.x] = sd[255];
}

__global__ __launch_bounds__(1024) void k_scan2(int* __restrict__ bs)
{
    __shared__ int sd[1024];
    const int t = threadIdx.x;
    int v = (t < SCAN_BLKS) ? bs[t] : 0;
    sd[t] = v;
    __syncthreads();
    for (int off = 1; off < 1024; off <<= 1) {
        int a = sd[t];
        int b = (t >= off) ? sd[t - off] : 0;
        __syncthreads();
        sd[t] = a + b;
        __syncthreads();
    }
    if (t < SCAN_BLKS) bs[t] = sd[t] - v;
}

__global__ __launch_bounds__(256) void k_scan3(int* __restrict__ s, const int* __restrict__ bs)
{
    const int i = blockIdx.x * 256 + threadIdx.x;
    if (i < NOUT + 1) s[i] += bs[blockIdx.x];
}

__global__ __launch_bounds__(256) void k_fill(const int* __restrict__ pout, const int* __restrict__ pin,
                                              int* __restrict__ cnt, const int* __restrict__ starts,
                                              int* __restrict__ entries)
{
    int i = blockIdx.x * 256 + threadIdx.x;
    if (i < NPAIR) {
        int o = pout[i];
        int old = atomicSub(&cnt[o], 1);
        int k = i / NOUT;
        entries[starts[o] + old - 1] = k * NIN + pin[i];
    }
}

// =============== gather-reduce: up_raw[o] (bf16) = sum Y[rid]; BN0 stats partials ===============
__global__ __launch_bounds__(256) void k_gather(
    const us8* __restrict__ Y8, const int* __restrict__ starts, const int* __restrict__ entries,
    us8* __restrict__ up8, float* __restrict__ parts)
{
    __shared__ float sS[16][16][8];
    __shared__ float sQ[16][16][8];
    const int t = threadIdx.x;
    const int rl = t >> 4, c8 = t & 15;
    float s[8], q[8];
    #pragma unroll
    for (int i = 0; i < 8; ++i) { s[i] = 0.f; q[i] = 0.f; }
    const int base = blockIdx.x * 64;
    #pragma unroll
    for (int it = 0; it < 4; ++it) {
        int o = base + it * 16 + rl;
        if (o < NOUT) {
            int j0 = starts[o], j1 = starts[o + 1];
            float a[8];
            #pragma unroll
            for (int i = 0; i < 8; ++i) a[i] = 0.f;
            int j = j0;
            for (; j + 1 < j1; j += 2) {
                int e0 = entries[j], e1 = entries[j + 1];
                us8 u0 = Y8[(size_t)e0 * 16 + c8];
                us8 u1 = Y8[(size_t)e1 * 16 + c8];
                #pragma unroll
                for (int i = 0; i < 8; ++i) a[i] += bff(u0[i]) + bff(u1[i]);
            }
            if (j < j1) {
                int e0 = entries[j];
                us8 u0 = Y8[(size_t)e0 * 16 + c8];
                #pragma unroll
                for (int i = 0; i < 8; ++i) a[i] += bff(u0[i]);
            }
            us8 o8;
            #pragma unroll
            for (int i = 0; i < 8; ++i) {
                o8[i] = fbf(a[i]);
                s[i] += a[i];
                q[i] = fmaf(a[i], a[i], q[i]);
            }
            up8[(size_t)o * 16 + c8] = o8;
        }
    }
    #pragma unroll
    for (int i = 0; i < 8; ++i) { sS[rl][c8][i] = s[i]; sQ[rl][c8][i] = q[i]; }
    __syncthreads();
    if (t < 128) {
        const int cc = t >> 3, ii = t & 7;
        float S = 0.f, Q = 0.f;
        #pragma unroll
        for (int r = 0; r < 16; ++r) { S += sS[r][cc][ii]; Q += sQ[r][cc][ii]; }
        parts[(size_t)blockIdx.x * 256 + t] = S;
        parts[(size_t)blockIdx.x * 256 + 128 + t] = Q;
    }
}

// =============== final: out = relu(bn2(h2)) + relu(bn0(up_raw)), fp32 out ===============
__global__ __launch_bounds__(256) void k_final(
    const us8* __restrict__ h2, const us8* __restrict__ upr, float* __restrict__ out,
    const float* __restrict__ stats2, const float* __restrict__ g2, const float* __restrict__ be2,
    const float* __restrict__ stats0, const float* __restrict__ g0, const float* __restrict__ b0)
{
    __shared__ float sc2[C], sh2[C], sc0[C], sh0[C];
    const int t = threadIdx.x;
    if (t < C) {
        float m2 = stats2[t] * (1.0f / NOUT);
        float v2 = stats2[C + t] * (1.0f / NOUT) - m2 * m2;
        float c2 = g2[t] * rsqrtf(v2 + EPSV);
        sc2[t] = c2; sh2[t] = fmaf(-m2, c2, be2[t]);
        float m0 = stats0[t] * (1.0f / NOUT);
        float v0 = stats0[C + t] * (1.0f / NOUT) - m0 * m0;
        float c0 = g0[t] * rsqrtf(v0 + EPSV);
        sc0[t] = c0; sh0[t] = fmaf(-m0, c0, b0[t]);
    }
    __syncthreads();
    const int idx0 = blockIdx.x * 256 + t;
    const int c8 = idx0 & 15;
    float l2s[8], l2h[8], l0s[8], l0h[8];
    #pragma unroll
    for (int i = 0; i < 8; ++i) {
        l2s[i] = sc2[c8 * 8 + i]; l2h[i] = sh2[c8 * 8 + i];
        l0s[i] = sc0[c8 * 8 + i]; l0h[i] = sh0[c8 * 8 + i];
    }
    const int total = NOUT * 16;
    for (int idx = idx0; idx < total; idx += gridDim.x * 256) {
        us8 h = h2[idx];
        us8 u = upr[idx];
        float o[8];
        #pragma unroll
        for (int i = 0; i < 8; ++i) {
            o[i] = fmaxf(fmaf(bff(h[i]), l2s[i], l2h[i]), 0.f)
                 + fmaxf(fmaf(bff(u[i]), l0s[i], l0h[i]), 0.f);
        }
        float4* dst = (float4*)&out[(size_t)idx * 8];
        dst[0] = make_float4(o[0], o[1], o[2], o[3]);
        dst[1] = make_float4(o[4], o[5], o[6], o[7]);
    }
}

extern "C" void kernel_launch(void* const* d_in, const int* in_sizes, int n_in,
                              void* d_out, int out_size, void* d_ws, size_t ws_size,
                              hipStream_t stream)
{
    const float* x    = (const float*)d_in[0];
    const float* skip = (const float*)d_in[1];
    const int*   pin  = (const int*)d_in[2];
    const int*   pout = (const int*)d_in[3];
    const float* Wup  = (const float*)d_in[4];
    const float* g0   = (const float*)d_in[5];
    const float* b0   = (const float*)d_in[6];
    const float* W1   = (const float*)d_in[7];
    const float* b1   = (const float*)d_in[8];
    const float* g1   = (const float*)d_in[9];
    const float* be1  = (const float*)d_in[10];
    const float* W2   = (const float*)d_in[11];
    const float* b2   = (const float*)d_in[12];
    const float* g2   = (const float*)d_in[13];
    const float* be2  = (const float*)d_in[14];
    float* outp = (float*)d_out;

    // ws layout: Y (82MB) reused by h1/h2 after gather; up_raw separate
    char* base = (char*)d_ws;
    unsigned short* Y      = (unsigned short*)base;               // 81,920,000 B
    unsigned short* h1     = (unsigned short*)base;               // alias (Y dead)
    unsigned short* h2     = (unsigned short*)(base + 40960000);  // alias (no overlap with h1)
    unsigned short* up_raw = (unsigned short*)(base + 81920000);  // 38,400,000 B
    char* p = base + 81920000 + 38400000;
    unsigned short* WT = (unsigned short*)p; p += (size_t)11 * 16384 * 2;
    int* counts    = (int*)p; p += (size_t)(NOUT + 4) * 4;
    int* starts    = (int*)p; p += (size_t)(NOUT + 4) * 4;
    int* entries   = (int*)p; p += (size_t)NPAIR * 4;
    int* blockSums = (int*)p; p += 4096;
    float* parts0  = (float*)p; p += (size_t)GATH * 256 * 4;
    float* parts1  = (float*)p; p += (size_t)GM * 256 * 4;
    float* parts2  = (float*)p; p += (size_t)GM * 256 * 4;
    float* stats   = (float*)p; p += 3 * 256 * 4;   // stats0 | stats1 | stats2

    hipMemsetAsync(counts, 0, (size_t)(NOUT + 4) * 4, stream);
    hipMemsetAsync(stats, 0, 3 * 256 * 4, stream);

    // 0. weights -> bf16 transposed
    k_prep_w<<<(11 * 16384 + 255) / 256, 256, 0, stream>>>(Wup, W1, W2, WT);

    // 1. Y[k] = x @ Wup[k]
    k_up<<<GUP, 256, 0, stream>>>(x, WT, Y);

    // 2. CSR build of pout
    const int gPair = (NPAIR + 255) / 256;
    k_hist<<<gPair, 256, 0, stream>>>(pout, counts);
    k_scan1<<<SCAN_BLKS, 256, 0, stream>>>(counts, starts, blockSums);
    k_scan2<<<1, 1024, 0, stream>>>(blockSums);
    k_scan3<<<SCAN_BLKS, 256, 0, stream>>>(starts, blockSums);
    k_fill<<<gPair, 256, 0, stream>>>(pout, pin, counts, starts, entries);

    // 3. gather-reduce -> up_raw bf16 + BN0 stats
    k_gather<<<GATH, 256, 0, stream>>>((const us8*)Y, starts, entries, (us8*)up_raw, parts0);
    k_reduce<<<16, 256, 0, stream>>>(parts0, GATH, stats);

    // 4. h1 = bf16( relu(bn0(up_raw)) @ W1[:128] + skip @ W1[128:] + b1 ) + BN1 stats
    k_mfma<2, true, true><<<GM2, 512, 0, stream>>>(
        up_raw, skip, WT + (size_t)8 * 16384, b1, h1, NOUT, stats, g0, b0, parts1);
    k_reduce<<<16, 256, 0, stream>>>(parts1, GM2, stats + 256);

    // 5. h2 = bf16( relu(bn1(h1)) @ W2 + b2 ) + BN2 stats
    k_mfma<1, true, true><<<GM2, 512, 0, stream>>>(
        h1, nullptr, WT + (size_t)10 * 16384, b2, h2, NOUT, stats + 256, g1, be1, parts2);
    k_reduce<<<16, 256, 0, stream>>>(parts2, GM2, stats + 512);

    // 6. out = relu(bn2(h2)) + relu(bn0(up_raw))
    k_final<<<1024, 256, 0, stream>>>((const us8*)h2, (const us8*)up_raw, outp,
        stats + 512, g2, be2, stats, g0, b0);
}